// Round 5
// baseline (459.227 us; speedup 1.0000x reference)
//
#include <hip/hip_runtime.h>
#include <stdint.h>

// ---------- bf16 helpers (raw ushort representation) ----------
__device__ __forceinline__ float bf2f(unsigned short u) {
  union { unsigned int i; float f; } v; v.i = ((unsigned int)u) << 16; return v.f;
}
__device__ __forceinline__ unsigned short f2bf(float f) {
  union { float f; unsigned int i; } v; v.f = f;
  unsigned int i = v.i;
  unsigned int r = (i + 0x7fffu + ((i >> 16) & 1u)) >> 16;  // RNE
  return (unsigned short)r;
}

typedef __bf16 bf16x8 __attribute__((ext_vector_type(8)));
typedef float f32x4 __attribute__((ext_vector_type(4)));
union ABfrag { int4 i4; bf16x8 v; };
union HVec { int4 i4; unsigned short u[8]; };

// Packed fragment layouts (lane = quad*16+mr):
//  A: Ap[((tm*KSTEPS + s)*64 + lane)*8 + j] = A[tm*16 + mr][s*32 + quad*8 + j]
//  B: Bp[((g*KSTEPS + s)*64 + lane)*8 + j] = W[s*32 + quad*8 + j][g*16 + mr]   (g = 16-col group)

// ---------- dtype detection (bf16-packed vs f32 inputs) ----------
__global__ __launch_bounds__(256) void k_detect(const unsigned int* __restrict__ x, int* flag) {
  __shared__ int cnt;
  if (threadIdx.x == 0) cnt = 0;
  __syncthreads();
  int c = 0;
  for (int i = threadIdx.x; i < 1024; i += 256) {
    unsigned int lo = x[i] & 0xFFFFu;
    int ex = (int)((lo >> 7) & 0xFF);
    if (ex >= 100 && ex <= 140) c++;
  }
  atomicAdd(&cnt, c);
  __syncthreads();
  if (threadIdx.x == 0) flag[0] = (cnt > 600) ? 1 : 0;  // 1 = bf16 inputs
}

// ---------- canonicalize small param tensors to f32 ----------
struct CanonDesc {
  const void* src[32];
  float* dst[32];
  int n[32];
  int cnt;
  int total;
};
__global__ __launch_bounds__(256) void k_canon(CanonDesc d, const int* __restrict__ flag) {
  int isbf = *flag;
  for (int idx = blockIdx.x * 256 + threadIdx.x; idx < d.total; idx += gridDim.x * 256) {
    int t = 0, off = idx;
    while (off >= d.n[t]) { off -= d.n[t]; ++t; }
    float v = isbf ? bf2f(((const unsigned short*)d.src[t])[off])
                   : ((const float*)d.src[t])[off];
    d.dst[t][off] = v;
  }
}

// ---------- x prep: raw -> f32 canon + packed-A bf16 (K=128) ----------
__global__ __launch_bounds__(256) void k_xprep(const void* __restrict__ x, float* __restrict__ xc,
                                               unsigned short* __restrict__ xp, int total,
                                               const int* __restrict__ flag) {
  int i = blockIdx.x * 256 + threadIdx.x;
  if (i >= total) return;
  int isbf = *flag;
  float v = isbf ? bf2f(((const unsigned short*)x)[i]) : ((const float*)x)[i];
  xc[i] = v;
  int row = i >> 7, c = i & 127;
  int tm = row >> 4, mr = row & 15;
  int s = c >> 5, quad = (c >> 3) & 3, j = c & 7;
  size_t idx = (((size_t)tm * 4 + s) * 64 + quad * 16 + mr) * 8 + j;
  xp[idx] = f2bf(v);
}

// ---------- weight pack: all 4 W's -> packed-B fragments, one launch ----------
__global__ __launch_bounds__(256) void k_wpack(const void* __restrict__ W1, const void* __restrict__ W2,
                                               const void* __restrict__ W3, const void* __restrict__ W4,
                                               unsigned short* __restrict__ P1, unsigned short* __restrict__ P2,
                                               unsigned short* __restrict__ P3, unsigned short* __restrict__ P4,
                                               const int* __restrict__ flag) {
  int u = blockIdx.x * 256 + threadIdx.x;   // 8-elem group index, 73728 total
  int isbf = *flag;
  const void* W; unsigned short* P; int K, N, lu;
  if (u < 32768)      { W = W1; P = P1; K = 128; N = 2048; lu = u; }
  else if (u < 36864) { W = W2; P = P2; K = 64;  N = 512;  lu = u - 32768; }
  else if (u < 69632) { W = W3; P = P3; K = 128; N = 2048; lu = u - 36864; }
  else                { W = W4; P = P4; K = 64;  N = 512;  lu = u - 69632; }
  int ksteps = K >> 5;
  int g = lu / (ksteps * 64);
  int rem = lu - g * (ksteps * 64);
  int s = rem >> 6, lane = rem & 63;
  int mr = lane & 15, quad = lane >> 4;
  int col = g * 16 + mr;
  int kbase = s * 32 + quad * 8;
#pragma unroll
  for (int j = 0; j < 8; ++j) {
    size_t src = (size_t)(kbase + j) * N + col;
    float v = isbf ? bf2f(((const unsigned short*)W)[src]) : ((const float*)W)[src];
    P[(size_t)lu * 8 + j] = f2bf(v);
  }
}

// ---------- CSR build ----------
__global__ __launch_bounds__(256) void k_deg_count(const int* __restrict__ ei, int* degA, int* degB, int E) {
  int e = blockIdx.x * 256 + threadIdx.x;
  if (e < E) { atomicAdd(&degA[ei[E + e]], 1); atomicAdd(&degB[ei[e]], 1); }
}
// exclusive scan of degA (block 0) / degB (block 1); adds +i for self-loops
__global__ __launch_bounds__(1024) void k_exscan2(const int* __restrict__ degA, const int* __restrict__ degB,
                                                  int* __restrict__ rowA, int* __restrict__ rowB, int n) {
  const int* deg = (blockIdx.x == 0) ? degA : degB;
  int* row = (blockIdx.x == 0) ? rowA : rowB;
  __shared__ int wsum[16], wbase[16];
  __shared__ int carry;
  if (threadIdx.x == 0) carry = 0;
  __syncthreads();
  int lane = threadIdx.x & 63, w = threadIdx.x >> 6;
  int chunks = (n + 1023) >> 10;
  for (int ch = 0; ch < chunks; ++ch) {
    int i = (ch << 10) + threadIdx.x;
    int v = (i < n) ? deg[i] : 0;
    int sc = v;
#pragma unroll
    for (int o = 1; o < 64; o <<= 1) { int t = __shfl_up(sc, o); if (lane >= o) sc += t; }
    if (lane == 63) wsum[w] = sc;
    __syncthreads();
    if (threadIdx.x < 16) {
      int v2 = wsum[threadIdx.x], s2 = v2;
#pragma unroll
      for (int o = 1; o < 16; o <<= 1) { int t = __shfl_up(s2, o); if (lane >= o) s2 += t; }
      wbase[threadIdx.x] = s2 - v2;
      if (threadIdx.x == 15) wsum[15] = s2;  // chunk total
    }
    __syncthreads();
    if (i < n) row[i] = carry + wbase[w] + (sc - v) + i;  // +i = self-loop slots
    __syncthreads();
    if (threadIdx.x == 0) carry += wsum[15];
    __syncthreads();
  }
  if (threadIdx.x == 0) row[n] = carry + n;
}
__global__ __launch_bounds__(256) void k_selfloop(const int* __restrict__ rowA, const int* __restrict__ rowB,
                                                 int* colA, int* colB, int* curA, int* curB, int n) {
  int i = blockIdx.x * 256 + threadIdx.x;
  if (i < n) {
    int ra = rowA[i]; colA[ra] = i; curA[i] = ra + 1;
    int rb = rowB[i]; colB[rb] = i; curB[i] = rb + 1;
  }
}
__global__ __launch_bounds__(256) void k_scatter(const int* __restrict__ ei, int* colA, int* colB,
                                                 int* curA, int* curB, int E) {
  int e = blockIdx.x * 256 + threadIdx.x;
  if (e < E) {
    int s = ei[e], d = ei[E + e];
    colA[atomicAdd(&curA[d], 1)] = s;
    colB[atomicAdd(&curB[s], 1)] = d;
  }
}

// ---------- bf16 MFMA matmul (packed A/B) + fused es/ed epilogue ----------
template<int CH, int KSTEPS>
__global__ __launch_bounds__(256) void k_mm_es(const unsigned short* __restrict__ Ap,
                                               const unsigned short* __restrict__ Bp,
                                               unsigned short* __restrict__ C,
                                               const float* __restrict__ a_s,
                                               const float* __restrict__ a_d,
                                               float* __restrict__ es, float* __restrict__ ed,
                                               int M, int N) {
  int wg = blockIdx.x * 4 + (threadIdx.x >> 6);
  int ntiles = N >> 6;
  int tm = wg / ntiles, tn = wg % ntiles;
  int lane = threadIdx.x & 63;
  int mr = lane & 15, quad = lane >> 4;
  const unsigned short* ap = Ap + ((size_t)tm * KSTEPS) * 512 + lane * 8;
  const unsigned short* bp = Bp + ((size_t)tn * 4 * KSTEPS) * 512 + lane * 8;
  f32x4 acc[4];
#pragma unroll
  for (int i = 0; i < 4; i++) acc[i] = (f32x4){0.f, 0.f, 0.f, 0.f};
#pragma unroll
  for (int s = 0; s < KSTEPS; ++s) {
    ABfrag a; a.i4 = *(const int4*)(ap + s * 512);
#pragma unroll
    for (int nt = 0; nt < 4; ++nt) {
      ABfrag b; b.i4 = *(const int4*)(bp + (size_t)(nt * KSTEPS + s) * 512);
      acc[nt] = __builtin_amdgcn_mfma_f32_16x16x32_bf16(a.v, b.v, acc[nt], 0, 0, 0);
    }
  }
#pragma unroll
  for (int nt = 0; nt < 4; ++nt)
#pragma unroll
    for (int r = 0; r < 4; ++r) {
      int row = tm * 16 + quad * 4 + r;
      int col = tn * 64 + nt * 16 + mr;
      C[(size_t)row * N + col] = f2bf(acc[nt][r]);
    }
  // ---- fused attention-logit epilogue ----
  if (CH == 64) {
    float pes[4] = {0.f,0.f,0.f,0.f}, ped[4] = {0.f,0.f,0.f,0.f};
    const float* asr = a_s + tn * 64;
    const float* adr = a_d + tn * 64;
#pragma unroll
    for (int nt = 0; nt < 4; ++nt) {
      float ws = asr[nt * 16 + mr], wd = adr[nt * 16 + mr];
#pragma unroll
      for (int r = 0; r < 4; ++r) { pes[r] += acc[nt][r] * ws; ped[r] += acc[nt][r] * wd; }
    }
#pragma unroll
    for (int m = 1; m < 16; m <<= 1)
#pragma unroll
      for (int r = 0; r < 4; ++r) {
        pes[r] += __shfl_xor(pes[r], m);
        ped[r] += __shfl_xor(ped[r], m);
      }
    if (mr == 0) {
#pragma unroll
      for (int r = 0; r < 4; ++r) {
        int row = tm * 16 + quad * 4 + r;
        es[row * 32 + tn] = pes[r];
        ed[row * 32 + tn] = ped[r];
      }
    }
  } else {
    float pes[4][4], ped[4][4];
#pragma unroll
    for (int nt = 0; nt < 4; ++nt) {
      float ws = a_s[(tn * 4 + nt) * 16 + mr];
      float wd = a_d[(tn * 4 + nt) * 16 + mr];
#pragma unroll
      for (int r = 0; r < 4; ++r) { pes[nt][r] = acc[nt][r] * ws; ped[nt][r] = acc[nt][r] * wd; }
    }
#pragma unroll
    for (int m = 1; m < 16; m <<= 1)
#pragma unroll
      for (int nt = 0; nt < 4; ++nt)
#pragma unroll
        for (int r = 0; r < 4; ++r) {
          pes[nt][r] += __shfl_xor(pes[nt][r], m);
          ped[nt][r] += __shfl_xor(ped[nt][r], m);
        }
    if (mr == 0) {
#pragma unroll
      for (int nt = 0; nt < 4; ++nt)
#pragma unroll
        for (int r = 0; r < 4; ++r) {
          int row = tm * 16 + quad * 4 + r;
          es[row * 32 + tn * 4 + nt] = pes[nt][r];
          ed[row * 32 + tn * 4 + nt] = ped[nt][r];
        }
    }
  }
}

// ---------- softmax M/Z + p per CSR slot: wave per node ----------
__global__ __launch_bounds__(256) void k_mz(const float* __restrict__ es, const float* __restrict__ ed,
                                            const int* __restrict__ rowp, const int* __restrict__ col,
                                            float* __restrict__ p, float* __restrict__ zinv, int n) {
  int wid = threadIdx.x >> 6, lane = threadIdx.x & 63;
  int i = blockIdx.x * 4 + wid;
  if (i >= n) return;
  int j2 = lane >> 5, h = lane & 31;
  int beg = rowp[i], end = rowp[i + 1];
  float edv = ed[i * 32 + h];
  float M = -1e30f;
  for (int j = beg + j2; j < end; j += 2) {
    float e = es[col[j] * 32 + h] + edv;
    e = (e > 0.f) ? e : 0.2f * e;
    M = fmaxf(M, e);
  }
  M = fmaxf(M, __shfl_xor(M, 32));
  float Z = 0.f;
  for (int j = beg + j2; j < end; j += 2) {
    float e = es[col[j] * 32 + h] + edv;
    e = (e > 0.f) ? e : 0.2f * e;
    float pj = __expf(e - M);
    p[(size_t)j * 32 + h] = pj;
    Z += pj;
  }
  Z += __shfl_xor(Z, 32);
  if (lane < 32) zinv[i * 32 + h] = 1.0f / Z;
}

// ---------- wide-load gather, C=64: wave reads whole h-row via b128 ----------
// load t (t<4): elements e = t*512 + lane*8 + k ; head = t*8 + (lane>>3); ch = (lane&7)*8 + k
__global__ __launch_bounds__(256) void k_gather64(const unsigned short* __restrict__ h,
                                                  const float* __restrict__ p,
                                                  const float* __restrict__ zinv,
                                                  const int* __restrict__ rowp, const int* __restrict__ col,
                                                  const float* __restrict__ bias,
                                                  unsigned short* __restrict__ outp, int n) {
  int i = blockIdx.x;
  int wid = threadIdx.x >> 6, lane = threadIdx.x & 63;
  int hsel = lane >> 3;
  __shared__ float red[4][64];
  int beg = rowp[i], end = rowp[i + 1];
  float acc[4][8];
#pragma unroll
  for (int t = 0; t < 4; ++t)
#pragma unroll
    for (int k = 0; k < 8; ++k) acc[t][k] = 0.f;
  for (int j = beg + wid; j < end; j += 4) {
    int s = col[j];
    const int4* hp = (const int4*)(h + (size_t)s * 2048);
    const float* pp = p + (size_t)j * 32 + hsel;
    HVec g[4];
    float pv[4];
#pragma unroll
    for (int t = 0; t < 4; ++t) { g[t].i4 = hp[t * 64 + lane]; pv[t] = pp[t * 8]; }
#pragma unroll
    for (int t = 0; t < 4; ++t)
#pragma unroll
      for (int k = 0; k < 8; ++k) acc[t][k] += pv[t] * bf2f(g[t].u[k]);
  }
  const float* zi = zinv + i * 32 + hsel;
  float v[8];
#pragma unroll
  for (int k = 0; k < 8; ++k) v[k] = 0.f;
#pragma unroll
  for (int t = 0; t < 4; ++t) {
    float z = zi[t * 8];
#pragma unroll
    for (int k = 0; k < 8; ++k) v[k] += acc[t][k] * z;
  }
#pragma unroll
  for (int m = 8; m < 64; m <<= 1)
#pragma unroll
    for (int k = 0; k < 8; ++k) v[k] += __shfl_xor(v[k], m);
  if (lane < 8) {
#pragma unroll
    for (int k = 0; k < 8; ++k) red[wid][lane * 8 + k] = v[k];
  }
  __syncthreads();
  if (threadIdx.x < 64) {
    int c = threadIdx.x;
    float t = red[0][c] + red[1][c] + red[2][c] + red[3][c];
    t = t * (1.f / 32.f) + bias[c];
    t = (t > 0.f) ? t : (__expf(t) - 1.f);  // elu
    // packed-A layout for the downstream K=64 GEMM
    int tm = i >> 4, mr = i & 15;
    int s = c >> 5, quad = (c >> 3) & 3, jj = c & 7;
    size_t idx = (((size_t)tm * 2 + s) * 64 + quad * 16 + mr) * 8 + jj;
    outp[idx] = f2bf(t);
  }
}

// ---------- wide-load gather, C=16: one b128 per edge per wave ----------
// elements e = lane*8 + k ; head = lane>>1 ; ch = (lane&1)*8 + k
__global__ __launch_bounds__(256) void k_gather16(const unsigned short* __restrict__ h,
                                                  const float* __restrict__ p,
                                                  const float* __restrict__ zinv,
                                                  const int* __restrict__ rowp, const int* __restrict__ col,
                                                  const float* __restrict__ bias,
                                                  void* __restrict__ outbase, size_t elem_off, int n,
                                                  const int* __restrict__ flag) {
  int i = blockIdx.x;
  int wid = threadIdx.x >> 6, lane = threadIdx.x & 63;
  int hh = lane >> 1;
  __shared__ float red[4][16];
  int beg = rowp[i], end = rowp[i + 1];
  float acc[8] = {0.f,0.f,0.f,0.f,0.f,0.f,0.f,0.f};
  for (int j = beg + wid; j < end; j += 4) {
    int s = col[j];
    HVec g;
    g.i4 = ((const int4*)(h + (size_t)s * 512))[lane];
    float pv = p[(size_t)j * 32 + hh];
#pragma unroll
    for (int k = 0; k < 8; ++k) acc[k] += pv * bf2f(g.u[k]);
  }
  float z = zinv[i * 32 + hh];
  float v[8];
#pragma unroll
  for (int k = 0; k < 8; ++k) v[k] = acc[k] * z;
#pragma unroll
  for (int m = 2; m < 64; m <<= 1)
#pragma unroll
    for (int k = 0; k < 8; ++k) v[k] += __shfl_xor(v[k], m);
  if (lane < 2) {
#pragma unroll
    for (int k = 0; k < 8; ++k) red[wid][lane * 8 + k] = v[k];
  }
  __syncthreads();
  if (threadIdx.x < 16) {
    float t = red[0][threadIdx.x] + red[1][threadIdx.x] + red[2][threadIdx.x] + red[3][threadIdx.x];
    t = t * (1.f / 32.f) + bias[threadIdx.x];
    t = (t > 0.f) ? t : (__expf(t) - 1.f);
    size_t o = elem_off + (size_t)i * 16 + threadIdx.x;
    if (*flag) ((unsigned short*)outbase)[o] = f2bf(t);
    else       ((float*)outbase)[o] = t;
  }
}

// ---------- fused residual network (f32) ----------
__global__ __launch_bounds__(256) void k_residual(const float* __restrict__ x,
    const float* __restrict__ rwa, const float* __restrict__ rba,
    const float* __restrict__ bn1g, const float* __restrict__ bn1b,
    const float* __restrict__ bn1m, const float* __restrict__ bn1v,
    const float* __restrict__ rwb, const float* __restrict__ rbb,
    const float* __restrict__ bn2g, const float* __restrict__ bn2b,
    const float* __restrict__ bn2m, const float* __restrict__ bn2v,
    const float* __restrict__ wsc, const float* __restrict__ bsc,
    const float* __restrict__ bnsg, const float* __restrict__ bnsb,
    const float* __restrict__ bnsm, const float* __restrict__ bnsv,
    const float* __restrict__ wfc, const float* __restrict__ bfc,
    void* __restrict__ outbase, size_t elem_off, int n, const int* __restrict__ flag) {
  __shared__ float xs[16][128];
  __shared__ float ha[16][16];
  __shared__ float tt[16][16];
  int nodebase = blockIdx.x * 16;
  for (int t = threadIdx.x; t < 16 * 128; t += 256)
    xs[t >> 7][t & 127] = x[(size_t)(nodebase + (t >> 7)) * 128 + (t & 127)];
  __syncthreads();
  int ni = threadIdx.x >> 4, c = threadIdx.x & 15;
  float ya = 0.f, ysc = 0.f;
  for (int k = 0; k < 128; ++k) {
    float xv = xs[ni][k];
    ya  += xv * rwa[k * 16 + c];
    ysc += xv * wsc[k * 16 + c];
  }
  ya += rba[c]; ysc += bsc[c];
  float s1 = bn1g[c] * rsqrtf(bn1v[c] + 1e-5f);
  ya = (ya - bn1m[c]) * s1 + bn1b[c];
  ya = fmaxf(ya, 0.f);
  float ss = bnsg[c] * rsqrtf(bnsv[c] + 1e-5f);
  ysc = (ysc - bnsm[c]) * ss + bnsb[c];
  ha[ni][c] = ya;
  __syncthreads();
  float h2 = rbb[c];
  for (int k = 0; k < 16; ++k) h2 += ha[ni][k] * rwb[k * 16 + c];
  float s2 = bn2g[c] * rsqrtf(bn2v[c] + 1e-5f);
  h2 = (h2 - bn2m[c]) * s2 + bn2b[c];
  tt[ni][c] = fmaxf(h2 + ysc, 0.f);
  __syncthreads();
  float o = bfc[c];
  for (int k = 0; k < 16; ++k) o += tt[ni][k] * wfc[k * 16 + c];
  size_t oo = elem_off + (size_t)(nodebase + ni) * 16 + c;
  if (*flag) ((unsigned short*)outbase)[oo] = f2bf(o);
  else       ((float*)outbase)[oo] = o;
}

extern "C" void kernel_launch(void* const* d_in, const int* in_sizes, int n_in,
                              void* d_out, int out_size, void* d_ws, size_t ws_size,
                              hipStream_t stream) {
  const int n = in_sizes[0] / 128;   // 10000
  const int E = in_sizes[1] / 2;     // 80000
  const int* ei = (const int*)d_in[1];

  char* wsp = (char*)d_ws; size_t off = 0;
  auto alloc = [&](size_t bytes) -> void* {
    void* p = wsp + off; off = (off + bytes + 255) & ~(size_t)255; return p;
  };
  int* flag = (int*)alloc(4);
  float* xc = (float*)alloc((size_t)n * 128 * 4);
  unsigned short* xp = (unsigned short*)alloc((size_t)n * 128 * 2);   // packed A, K=128
  unsigned short* W1p = (unsigned short*)alloc((size_t)2048 * 128 * 2);
  unsigned short* W2p = (unsigned short*)alloc((size_t)512 * 64 * 2);
  unsigned short* W3p = (unsigned short*)alloc((size_t)2048 * 128 * 2);
  unsigned short* W4p = (unsigned short*)alloc((size_t)512 * 64 * 2);
  unsigned short* hbuf = (unsigned short*)alloc((size_t)n * 2048 * 2);
  unsigned short* hbuf2 = hbuf;  // reuse (lifetimes disjoint)
  float* es = (float*)alloc((size_t)n * 32 * 4);
  float* ed = (float*)alloc((size_t)n * 32 * 4);
  float* pbuf = (float*)alloc((size_t)(E + n) * 32 * 4);
  float* zinv = (float*)alloc((size_t)n * 32 * 4);
  unsigned short* xsp = (unsigned short*)alloc((size_t)n * 64 * 2);   // packed A, K=64
  unsigned short* xtp = (unsigned short*)alloc((size_t)n * 64 * 2);
  int* rowA = (int*)alloc((size_t)(n + 1) * 4);
  int* rowB = (int*)alloc((size_t)(n + 1) * 4);
  int* colA = (int*)alloc((size_t)(E + n) * 4);
  int* colB = (int*)alloc((size_t)(E + n) * 4);
  int* degAB = (int*)alloc((size_t)2 * n * 4);
  int* degA = degAB, * degB = degAB + n;
  int* curA = (int*)alloc((size_t)n * 4);
  int* curB = (int*)alloc((size_t)n * 4);

  static const int cidx[32] = {3,4,5, 7,8,9, 11,12,13, 15,16,17,
                               18,19,20,21,22,23,24,25,26,27,28,29,
                               30,31,32,33,34,35,36,37};
  CanonDesc cd; cd.cnt = 32; cd.total = 0;
  float* canon[38] = {nullptr};
  for (int t = 0; t < 32; ++t) {
    int ii = cidx[t];
    canon[ii] = (float*)alloc((size_t)in_sizes[ii] * 4);
    cd.src[t] = d_in[ii];
    cd.dst[t] = canon[ii];
    cd.n[t] = in_sizes[ii];
    cd.total += in_sizes[ii];
  }
  (void)ws_size; (void)n_in; (void)out_size;

  // ---- dtype detect + canonicalize + packs ----
  k_detect<<<1, 256, 0, stream>>>((const unsigned int*)d_in[0], flag);
  k_canon<<<64, 256, 0, stream>>>(cd, flag);
  k_xprep<<<(n * 128) / 256, 256, 0, stream>>>(d_in[0], xc, xp, n * 128, flag);
  k_wpack<<<288, 256, 0, stream>>>(d_in[2], d_in[6], d_in[10], d_in[14],
                                   W1p, W2p, W3p, W4p, flag);

  // ---- CSR build (both flows) ----
  hipMemsetAsync(degAB, 0, (size_t)2 * n * 4, stream);
  k_deg_count<<<(E + 255) / 256, 256, 0, stream>>>(ei, degA, degB, E);
  k_exscan2<<<2, 1024, 0, stream>>>(degA, degB, rowA, rowB, n);
  k_selfloop<<<(n + 255) / 256, 256, 0, stream>>>(rowA, rowB, colA, colB, curA, curB, n);
  k_scatter<<<(E + 255) / 256, 256, 0, stream>>>(ei, colA, colB, curA, curB, E);

  const int mt = n / 16;  // 625
  // ---- Layer 1 (s2t, C=64): x_s ----
  k_mm_es<64,4><<<mt * 32 / 4, 256, 0, stream>>>(xp, W1p, hbuf, canon[3], canon[4], es, ed, n, 2048);
  k_mz<<<(n + 3) / 4, 256, 0, stream>>>(es, ed, rowA, colA, pbuf, zinv, n);
  k_gather64<<<n, 256, 0, stream>>>(hbuf, pbuf, zinv, rowA, colA, canon[5], xsp, n);
  // ---- Layer 2 (s2t, C=16): x_in -> out[0] ----
  k_mm_es<16,2><<<mt * 8 / 4, 256, 0, stream>>>(xsp, W2p, hbuf2, canon[7], canon[8], es, ed, n, 512);
  k_mz<<<(n + 3) / 4, 256, 0, stream>>>(es, ed, rowA, colA, pbuf, zinv, n);
  k_gather16<<<n, 256, 0, stream>>>(hbuf2, pbuf, zinv, rowA, colA, canon[9], d_out, 0, n, flag);
  // ---- Layer 3 (t2s, C=64): x_t ----
  k_mm_es<64,4><<<mt * 32 / 4, 256, 0, stream>>>(xp, W3p, hbuf, canon[11], canon[12], es, ed, n, 2048);
  k_mz<<<(n + 3) / 4, 256, 0, stream>>>(es, ed, rowB, colB, pbuf, zinv, n);
  k_gather64<<<n, 256, 0, stream>>>(hbuf, pbuf, zinv, rowB, colB, canon[13], xtp, n);
  // ---- Layer 4 (t2s, C=16): x_out -> out[1] ----
  k_mm_es<16,2><<<mt * 8 / 4, 256, 0, stream>>>(xtp, W4p, hbuf2, canon[15], canon[16], es, ed, n, 512);
  k_mz<<<(n + 3) / 4, 256, 0, stream>>>(es, ed, rowB, colB, pbuf, zinv, n);
  k_gather16<<<n, 256, 0, stream>>>(hbuf2, pbuf, zinv, rowB, colB, canon[17], d_out, (size_t)n * 16, n, flag);
  // ---- Residual MLP: x_self -> out[2] ----
  k_residual<<<n / 16, 256, 0, stream>>>(xc,
      canon[18], canon[19], canon[20], canon[21], canon[22], canon[23],
      canon[24], canon[25], canon[26], canon[27], canon[28], canon[29],
      canon[30], canon[31], canon[32], canon[33], canon[34], canon[35],
      canon[36], canon[37],
      d_out, (size_t)2 * n * 16, n, flag);
}

// Round 6
// 449.492 us; speedup vs baseline: 1.0217x; 1.0217x over previous
//
#include <hip/hip_runtime.h>
#include <stdint.h>

// ---------- bf16 helpers ----------
__device__ __forceinline__ float bf2f(unsigned short u) {
  union { unsigned int i; float f; } v; v.i = ((unsigned int)u) << 16; return v.f;
}
__device__ __forceinline__ unsigned short f2bf(float f) {
  union { float f; unsigned int i; } v; v.f = f;
  unsigned int i = v.i;
  unsigned int r = (i + 0x7fffu + ((i >> 16) & 1u)) >> 16;  // RNE
  return (unsigned short)r;
}

typedef __bf16 bf16x8 __attribute__((ext_vector_type(8)));
typedef float f32x4 __attribute__((ext_vector_type(4)));
union ABfrag { int4 i4; bf16x8 v; };

// ---------- fp8 e4m3fn (OCP) helpers: HW path on gfx950, SW fallback ----------
#if __has_builtin(__builtin_amdgcn_cvt_pk_fp8_f32) && __has_builtin(__builtin_amdgcn_cvt_pk_f32_fp8)
#define HW_FP8 1
#else
#define HW_FP8 0
#endif

__device__ __forceinline__ unsigned char f2fp8_sw(float f) {
  union { float f; unsigned int u; } v; v.f = f;
  unsigned int s = (v.u >> 24) & 0x80;
  float a = fabsf(f);
  if (a >= 448.f) return (unsigned char)(s | 0x7E);
  v.f = a;
  int ex = (int)(v.u >> 23);
  unsigned int man = v.u & 0x7FFFFFu;
  if (ex >= 121) {
    unsigned int val = ((unsigned int)(ex - 120) << 3) | (man >> 20);
    unsigned int rem = man & 0xFFFFFu;
    if (rem > 0x80000u || (rem == 0x80000u && (val & 1))) val++;
    if (val > 0x7E) val = 0x7E;
    return (unsigned char)(s | val);
  }
  int q = (int)(a * 512.f + 0.5f);
  if (q > 8) q = 8;
  return (unsigned char)(s | (unsigned int)q);
}
__device__ __forceinline__ float fp8dec_sw(unsigned char c) {
  unsigned int e = (c >> 3) & 15u, m = c & 7u;
  float v;
  if (e) { union { unsigned int u; float f; } x; x.u = ((e + 120) << 23) | (m << 20); v = x.f; }
  else v = (float)m * 0.001953125f;
  return (c & 0x80) ? -v : v;
}
__device__ __forceinline__ unsigned char f2fp8(float f) {
#if HW_FP8
  int v = __builtin_amdgcn_cvt_pk_fp8_f32(f, f, 0, false);
  return (unsigned char)(v & 0xFF);
#else
  return f2fp8_sw(f);
#endif
}
__device__ __forceinline__ void dec16(int4 g, float o[16]) {
#if HW_FP8
  { auto p = __builtin_amdgcn_cvt_pk_f32_fp8(g.x, false); o[0]=p[0]; o[1]=p[1]; }
  { auto p = __builtin_amdgcn_cvt_pk_f32_fp8(g.x, true ); o[2]=p[0]; o[3]=p[1]; }
  { auto p = __builtin_amdgcn_cvt_pk_f32_fp8(g.y, false); o[4]=p[0]; o[5]=p[1]; }
  { auto p = __builtin_amdgcn_cvt_pk_f32_fp8(g.y, true ); o[6]=p[0]; o[7]=p[1]; }
  { auto p = __builtin_amdgcn_cvt_pk_f32_fp8(g.z, false); o[8]=p[0]; o[9]=p[1]; }
  { auto p = __builtin_amdgcn_cvt_pk_f32_fp8(g.z, true ); o[10]=p[0]; o[11]=p[1]; }
  { auto p = __builtin_amdgcn_cvt_pk_f32_fp8(g.w, false); o[12]=p[0]; o[13]=p[1]; }
  { auto p = __builtin_amdgcn_cvt_pk_f32_fp8(g.w, true ); o[14]=p[0]; o[15]=p[1]; }
#else
  unsigned int w[4] = {(unsigned)g.x, (unsigned)g.y, (unsigned)g.z, (unsigned)g.w};
#pragma unroll
  for (int d = 0; d < 4; ++d)
#pragma unroll
    for (int b = 0; b < 4; ++b) o[d*4+b] = fp8dec_sw((unsigned char)((w[d] >> (b*8)) & 0xFF));
#endif
}

// ---------- dtype detection (bf16-packed vs f32 inputs) ----------
__global__ __launch_bounds__(256) void k_detect(const unsigned int* __restrict__ x, int* flag) {
  __shared__ int cnt;
  if (threadIdx.x == 0) cnt = 0;
  __syncthreads();
  int c = 0;
  for (int i = threadIdx.x; i < 1024; i += 256) {
    unsigned int lo = x[i] & 0xFFFFu;
    int ex = (int)((lo >> 7) & 0xFF);
    if (ex >= 100 && ex <= 140) c++;
  }
  atomicAdd(&cnt, c);
  __syncthreads();
  if (threadIdx.x == 0) flag[0] = (cnt > 600) ? 1 : 0;  // 1 = bf16 inputs
}

// ---------- unified prep: xprep + wpack + canon + deg-zero ----------
struct PrepDesc {
  const void* csrc[32]; float* cdst[32]; int cn[32];
  const void* x; float* xc; unsigned short* xp;
  const void* W1; const void* W2; const void* W3; const void* W4;
  unsigned short* P1; unsigned short* P2; unsigned short* P3; unsigned short* P4;
  int* degAB;
  int nxb;      // blocks for xprep
  int xtotal;   // n*128
  int ctotal;   // canon elements
  int ndeg2;    // 2*n
};
__global__ __launch_bounds__(256) void k_prep(PrepDesc d, const int* __restrict__ flag) {
  int isbf = *flag;
  int b = blockIdx.x;
  if (b < d.nxb) {
    // ---- x: raw -> f32 canon + packed-A bf16 (K=128) ----
    int i = b * 256 + threadIdx.x;
    if (i < d.xtotal) {
      float v = isbf ? bf2f(((const unsigned short*)d.x)[i]) : ((const float*)d.x)[i];
      d.xc[i] = v;
      int row = i >> 7, c = i & 127;
      int tm = row >> 4, mr = row & 15;
      int s = c >> 5, quad = (c >> 3) & 3, j = c & 7;
      size_t idx = (((size_t)tm * 4 + s) * 64 + quad * 16 + mr) * 8 + j;
      d.xp[idx] = f2bf(v);
    }
    return;
  }
  b -= d.nxb;
  if (b < 288) {
    // ---- weight pack -> bf16 B fragments ----
    int u = b * 256 + threadIdx.x;   // 73728 total
    const void* W; unsigned short* P; int K, N, lu;
    if (u < 32768)      { W = d.W1; P = d.P1; K = 128; N = 2048; lu = u; }
    else if (u < 36864) { W = d.W2; P = d.P2; K = 64;  N = 512;  lu = u - 32768; }
    else if (u < 69632) { W = d.W3; P = d.P3; K = 128; N = 2048; lu = u - 36864; }
    else                { W = d.W4; P = d.P4; K = 64;  N = 512;  lu = u - 69632; }
    int ksteps = K >> 5;
    int g = lu / (ksteps * 64);
    int rem = lu - g * (ksteps * 64);
    int s = rem >> 6, lane = rem & 63;
    int mr = lane & 15, quad = lane >> 4;
    int col = g * 16 + mr;
    int kbase = s * 32 + quad * 8;
#pragma unroll
    for (int j = 0; j < 8; ++j) {
      size_t src = (size_t)(kbase + j) * N + col;
      float v = isbf ? bf2f(((const unsigned short*)W)[src]) : ((const float*)W)[src];
      P[(size_t)lu * 8 + j] = f2bf(v);
    }
    return;
  }
  b -= 288;
  if (b < 4) {
    // ---- canonicalize small params to f32 ----
    for (int idx = b * 256 + threadIdx.x; idx < d.ctotal; idx += 4 * 256) {
      int t = 0, off = idx;
      while (off >= d.cn[t]) { off -= d.cn[t]; ++t; }
      float v = isbf ? bf2f(((const unsigned short*)d.csrc[t])[off])
                     : ((const float*)d.csrc[t])[off];
      d.cdst[t][off] = v;
    }
    return;
  }
  b -= 4;
  // ---- zero degree arrays (8 blocks) ----
  for (int idx = b * 256 + threadIdx.x; idx < d.ndeg2; idx += 8 * 256) d.degAB[idx] = 0;
}

// ---------- CSR build ----------
__global__ __launch_bounds__(256) void k_deg_count(const int* __restrict__ ei, int* degA, int* degB, int E) {
  int e = blockIdx.x * 256 + threadIdx.x;
  if (e < E) { atomicAdd(&degA[ei[E + e]], 1); atomicAdd(&degB[ei[e]], 1); }
}
__global__ __launch_bounds__(1024) void k_exscan2(const int* __restrict__ degA, const int* __restrict__ degB,
                                                  int* __restrict__ rowA, int* __restrict__ rowB, int n) {
  const int* deg = (blockIdx.x == 0) ? degA : degB;
  int* row = (blockIdx.x == 0) ? rowA : rowB;
  __shared__ int wsum[16], wbase[16];
  __shared__ int carry;
  if (threadIdx.x == 0) carry = 0;
  __syncthreads();
  int lane = threadIdx.x & 63, w = threadIdx.x >> 6;
  int chunks = (n + 1023) >> 10;
  for (int ch = 0; ch < chunks; ++ch) {
    int i = (ch << 10) + threadIdx.x;
    int v = (i < n) ? deg[i] : 0;
    int sc = v;
#pragma unroll
    for (int o = 1; o < 64; o <<= 1) { int t = __shfl_up(sc, o); if (lane >= o) sc += t; }
    if (lane == 63) wsum[w] = sc;
    __syncthreads();
    if (threadIdx.x < 16) {
      int v2 = wsum[threadIdx.x], s2 = v2;
#pragma unroll
      for (int o = 1; o < 16; o <<= 1) { int t = __shfl_up(s2, o); if (lane >= o) s2 += t; }
      wbase[threadIdx.x] = s2 - v2;
      if (threadIdx.x == 15) wsum[15] = s2;
    }
    __syncthreads();
    if (i < n) row[i] = carry + wbase[w] + (sc - v) + i;  // +i = self-loop slots
    __syncthreads();
    if (threadIdx.x == 0) carry += wsum[15];
    __syncthreads();
  }
  if (threadIdx.x == 0) row[n] = carry + n;
}
__global__ __launch_bounds__(256) void k_selfloop(const int* __restrict__ rowA, const int* __restrict__ rowB,
                                                 int* colA, int* colB, int* curA, int* curB, int n) {
  int i = blockIdx.x * 256 + threadIdx.x;
  if (i < n) {
    int ra = rowA[i]; colA[ra] = i; curA[i] = ra + 1;
    int rb = rowB[i]; colB[rb] = i; curB[i] = rb + 1;
  }
}
__global__ __launch_bounds__(256) void k_scatter(const int* __restrict__ ei, int* colA, int* colB,
                                                 int* curA, int* curB, int E) {
  int e = blockIdx.x * 256 + threadIdx.x;
  if (e < E) {
    int s = ei[e], d = ei[E + e];
    colA[atomicAdd(&curA[d], 1)] = s;
    colB[atomicAdd(&curB[s], 1)] = d;
  }
}

// ---------- bf16 MFMA matmul (packed A/B) -> fp8 C + fused es/ed epilogue ----------
template<int CH, int KSTEPS>
__global__ __launch_bounds__(256) void k_mm_es(const unsigned short* __restrict__ Ap,
                                               const unsigned short* __restrict__ Bp,
                                               unsigned char* __restrict__ C,   // fp8 [M][N]
                                               const float* __restrict__ a_s,
                                               const float* __restrict__ a_d,
                                               float* __restrict__ es, float* __restrict__ ed,
                                               int M, int N) {
  int wg = blockIdx.x * 4 + (threadIdx.x >> 6);
  int ntiles = N >> 6;
  int tm = wg / ntiles, tn = wg % ntiles;
  int lane = threadIdx.x & 63;
  int mr = lane & 15, quad = lane >> 4;
  const unsigned short* ap = Ap + ((size_t)tm * KSTEPS) * 512 + lane * 8;
  const unsigned short* bp = Bp + ((size_t)tn * 4 * KSTEPS) * 512 + lane * 8;
  f32x4 acc[4];
#pragma unroll
  for (int i = 0; i < 4; i++) acc[i] = (f32x4){0.f, 0.f, 0.f, 0.f};
#pragma unroll
  for (int s = 0; s < KSTEPS; ++s) {
    ABfrag a; a.i4 = *(const int4*)(ap + s * 512);
#pragma unroll
    for (int nt = 0; nt < 4; ++nt) {
      ABfrag b; b.i4 = *(const int4*)(bp + (size_t)(nt * KSTEPS + s) * 512);
      acc[nt] = __builtin_amdgcn_mfma_f32_16x16x32_bf16(a.v, b.v, acc[nt], 0, 0, 0);
    }
  }
#pragma unroll
  for (int nt = 0; nt < 4; ++nt)
#pragma unroll
    for (int r = 0; r < 4; ++r) {
      int row = tm * 16 + quad * 4 + r;
      int col = tn * 64 + nt * 16 + mr;
      C[(size_t)row * N + col] = f2fp8(acc[nt][r]);
    }
  // ---- fused attention-logit epilogue ----
  if (CH == 64) {
    float pes[4] = {0.f,0.f,0.f,0.f}, ped[4] = {0.f,0.f,0.f,0.f};
    const float* asr = a_s + tn * 64;
    const float* adr = a_d + tn * 64;
#pragma unroll
    for (int nt = 0; nt < 4; ++nt) {
      float ws = asr[nt * 16 + mr], wd = adr[nt * 16 + mr];
#pragma unroll
      for (int r = 0; r < 4; ++r) { pes[r] += acc[nt][r] * ws; ped[r] += acc[nt][r] * wd; }
    }
#pragma unroll
    for (int m = 1; m < 16; m <<= 1)
#pragma unroll
      for (int r = 0; r < 4; ++r) {
        pes[r] += __shfl_xor(pes[r], m);
        ped[r] += __shfl_xor(ped[r], m);
      }
    if (mr == 0) {
#pragma unroll
      for (int r = 0; r < 4; ++r) {
        int row = tm * 16 + quad * 4 + r;
        es[row * 32 + tn] = pes[r];
        ed[row * 32 + tn] = ped[r];
      }
    }
  } else {
    float pes[4][4], ped[4][4];
#pragma unroll
    for (int nt = 0; nt < 4; ++nt) {
      float ws = a_s[(tn * 4 + nt) * 16 + mr];
      float wd = a_d[(tn * 4 + nt) * 16 + mr];
#pragma unroll
      for (int r = 0; r < 4; ++r) { pes[nt][r] = acc[nt][r] * ws; ped[nt][r] = acc[nt][r] * wd; }
    }
#pragma unroll
    for (int m = 1; m < 16; m <<= 1)
#pragma unroll
      for (int nt = 0; nt < 4; ++nt)
#pragma unroll
        for (int r = 0; r < 4; ++r) {
          pes[nt][r] += __shfl_xor(pes[nt][r], m);
          ped[nt][r] += __shfl_xor(ped[nt][r], m);
        }
    if (mr == 0) {
#pragma unroll
      for (int nt = 0; nt < 4; ++nt)
#pragma unroll
        for (int r = 0; r < 4; ++r) {
          int row = tm * 16 + quad * 4 + r;
          es[row * 32 + tn * 4 + nt] = pes[nt][r];
          ed[row * 32 + tn * 4 + nt] = ped[nt][r];
        }
    }
  }
}

__device__ __forceinline__ float lrelu_clamp(float e) {
  e = (e > 0.f) ? e : 0.2f * e;
  return fminf(e, 80.f);
}

// ---------- fused softmax+gather, C=64, fp8 h [n][2048] ----------
// no max-subtraction (logits bounded; clamped at 80); single pass accumulates Z and p*h
__global__ __launch_bounds__(256) void k_gather64(const unsigned char* __restrict__ h,
                                                  const float* __restrict__ es, const float* __restrict__ ed,
                                                  const int* __restrict__ rowp, const int* __restrict__ col,
                                                  const float* __restrict__ bias,
                                                  unsigned short* __restrict__ outp, int n) {
  int i = blockIdx.x;
  int wid = threadIdx.x >> 6, lane = threadIdx.x & 63;
  __shared__ float edsh[32], Zsh[32];
  __shared__ float zacc[4][32];
  __shared__ float red[4][64];
  if (threadIdx.x < 32) edsh[threadIdx.x] = ed[i * 32 + threadIdx.x];
  __syncthreads();
  int beg = rowp[i], end = rowp[i + 1];
  int hd0 = lane >> 2, hd1 = 16 + (lane >> 2);
  float e0 = edsh[hd0], e1 = edsh[hd1];
  float acc[2][16];
#pragma unroll
  for (int t = 0; t < 2; ++t)
#pragma unroll
    for (int k = 0; k < 16; ++k) acc[t][k] = 0.f;
  float Z0 = 0.f, Z1 = 0.f;
  for (int j = beg + wid; j < end; j += 4) {
    int s = col[j];
    const int4* hp = (const int4*)(h + (size_t)s * 2048);
    int4 g0 = hp[lane];
    int4 g1 = hp[64 + lane];
    float q0 = __expf(lrelu_clamp(es[s * 32 + hd0] + e0));
    float q1 = __expf(lrelu_clamp(es[s * 32 + hd1] + e1));
    Z0 += q0; Z1 += q1;
    float d0[16], d1[16];
    dec16(g0, d0); dec16(g1, d1);
#pragma unroll
    for (int k = 0; k < 16; ++k) { acc[0][k] += q0 * d0[k]; acc[1][k] += q1 * d1[k]; }
  }
  if ((lane & 3) == 0) { zacc[wid][hd0] = Z0; zacc[wid][hd1] = Z1; }
  __syncthreads();
  if (threadIdx.x < 32) {
    int hh = threadIdx.x;
    Zsh[hh] = 1.0f / (zacc[0][hh] + zacc[1][hh] + zacc[2][hh] + zacc[3][hh]);
  }
  __syncthreads();
  float zi0 = Zsh[hd0], zi1 = Zsh[hd1];
  float v[16];
#pragma unroll
  for (int k = 0; k < 16; ++k) v[k] = acc[0][k] * zi0 + acc[1][k] * zi1;
#pragma unroll
  for (int m = 4; m < 64; m <<= 1)
#pragma unroll
    for (int k = 0; k < 16; ++k) v[k] += __shfl_xor(v[k], m);
  if (lane < 4) {
#pragma unroll
    for (int k = 0; k < 16; ++k) red[wid][lane * 16 + k] = v[k];
  }
  __syncthreads();
  if (threadIdx.x < 64) {
    int c = threadIdx.x;
    float t = red[0][c] + red[1][c] + red[2][c] + red[3][c];
    t = t * (1.f / 32.f) + bias[c];
    t = (t > 0.f) ? t : (__expf(t) - 1.f);  // elu
    int tm = i >> 4, mr = i & 15;
    int s = c >> 5, quad = (c >> 3) & 3, jj = c & 7;
    size_t idx = (((size_t)tm * 2 + s) * 64 + quad * 16 + mr) * 8 + jj;
    outp[idx] = f2bf(t);   // packed-A bf16 for downstream K=64 GEMM
  }
}

// ---------- fused softmax+gather, C=16, fp8 h [n][512] -> final output ----------
__global__ __launch_bounds__(256) void k_gather16(const unsigned char* __restrict__ h,
                                                  const float* __restrict__ es, const float* __restrict__ ed,
                                                  const int* __restrict__ rowp, const int* __restrict__ col,
                                                  const float* __restrict__ bias,
                                                  void* __restrict__ outbase, size_t elem_off, int n,
                                                  const int* __restrict__ flag) {
  int i = blockIdx.x;
  int wid = threadIdx.x >> 6, lane = threadIdx.x & 63;
  int hh = lane & 31, j2 = lane >> 5;
  __shared__ float edsh[32], Zsh[32];
  __shared__ float zacc[4][32];
  __shared__ float red[4][16];
  if (threadIdx.x < 32) edsh[threadIdx.x] = ed[i * 32 + threadIdx.x];
  __syncthreads();
  int beg = rowp[i], end = rowp[i + 1];
  float ev = edsh[hh];
  float acc[16];
#pragma unroll
  for (int k = 0; k < 16; ++k) acc[k] = 0.f;
  float Z = 0.f;
  for (int j = beg + wid * 2 + j2; j < end; j += 8) {
    int s = col[j];
    int4 g = ((const int4*)(h + (size_t)s * 512))[hh];
    float q = __expf(lrelu_clamp(es[s * 32 + hh] + ev));
    Z += q;
    float d[16];
    dec16(g, d);
#pragma unroll
    for (int k = 0; k < 16; ++k) acc[k] += q * d[k];
  }
  Z += __shfl_xor(Z, 32);
  if (lane < 32) zacc[wid][hh] = Z;
  __syncthreads();
  if (threadIdx.x < 32)
    Zsh[threadIdx.x] = 1.0f / (zacc[0][threadIdx.x] + zacc[1][threadIdx.x] + zacc[2][threadIdx.x] + zacc[3][threadIdx.x]);
  __syncthreads();
  float zi = Zsh[hh];
  float v[16];
#pragma unroll
  for (int k = 0; k < 16; ++k) v[k] = acc[k] * zi;
#pragma unroll
  for (int m = 1; m < 64; m <<= 1)
#pragma unroll
    for (int k = 0; k < 16; ++k) v[k] += __shfl_xor(v[k], m);
  if (lane == 0) {
#pragma unroll
    for (int k = 0; k < 16; ++k) red[wid][k] = v[k];
  }
  __syncthreads();
  if (threadIdx.x < 16) {
    float t = red[0][threadIdx.x] + red[1][threadIdx.x] + red[2][threadIdx.x] + red[3][threadIdx.x];
    t = t * (1.f / 32.f) + bias[threadIdx.x];
    t = (t > 0.f) ? t : (__expf(t) - 1.f);
    size_t o = elem_off + (size_t)i * 16 + threadIdx.x;
    if (*flag) ((unsigned short*)outbase)[o] = f2bf(t);
    else       ((float*)outbase)[o] = t;
  }
}

// ---------- fused residual network (f32) ----------
__global__ __launch_bounds__(256) void k_residual(const float* __restrict__ x,
    const float* __restrict__ rwa, const float* __restrict__ rba,
    const float* __restrict__ bn1g, const float* __restrict__ bn1b,
    const float* __restrict__ bn1m, const float* __restrict__ bn1v,
    const float* __restrict__ rwb, const float* __restrict__ rbb,
    const float* __restrict__ bn2g, const float* __restrict__ bn2b,
    const float* __restrict__ bn2m, const float* __restrict__ bn2v,
    const float* __restrict__ wsc, const float* __restrict__ bsc,
    const float* __restrict__ bnsg, const float* __restrict__ bnsb,
    const float* __restrict__ bnsm, const float* __restrict__ bnsv,
    const float* __restrict__ wfc, const float* __restrict__ bfc,
    void* __restrict__ outbase, size_t elem_off, int n, const int* __restrict__ flag) {
  __shared__ float xs[16][128];
  __shared__ float ha[16][16];
  __shared__ float tt[16][16];
  int nodebase = blockIdx.x * 16;
  for (int t = threadIdx.x; t < 16 * 128; t += 256)
    xs[t >> 7][t & 127] = x[(size_t)(nodebase + (t >> 7)) * 128 + (t & 127)];
  __syncthreads();
  int ni = threadIdx.x >> 4, c = threadIdx.x & 15;
  float ya = 0.f, ysc = 0.f;
  for (int k = 0; k < 128; ++k) {
    float xv = xs[ni][k];
    ya  += xv * rwa[k * 16 + c];
    ysc += xv * wsc[k * 16 + c];
  }
  ya += rba[c]; ysc += bsc[c];
  float s1 = bn1g[c] * rsqrtf(bn1v[c] + 1e-5f);
  ya = (ya - bn1m[c]) * s1 + bn1b[c];
  ya = fmaxf(ya, 0.f);
  float ss = bnsg[c] * rsqrtf(bnsv[c] + 1e-5f);
  ysc = (ysc - bnsm[c]) * ss + bnsb[c];
  ha[ni][c] = ya;
  __syncthreads();
  float h2 = rbb[c];
  for (int k = 0; k < 16; ++k) h2 += ha[ni][k] * rwb[k * 16 + c];
  float s2 = bn2g[c] * rsqrtf(bn2v[c] + 1e-5f);
  h2 = (h2 - bn2m[c]) * s2 + bn2b[c];
  tt[ni][c] = fmaxf(h2 + ysc, 0.f);
  __syncthreads();
  float o = bfc[c];
  for (int k = 0; k < 16; ++k) o += tt[ni][k] * wfc[k * 16 + c];
  size_t oo = elem_off + (size_t)(nodebase + ni) * 16 + c;
  if (*flag) ((unsigned short*)outbase)[oo] = f2bf(o);
  else       ((float*)outbase)[oo] = o;
}

extern "C" void kernel_launch(void* const* d_in, const int* in_sizes, int n_in,
                              void* d_out, int out_size, void* d_ws, size_t ws_size,
                              hipStream_t stream) {
  const int n = in_sizes[0] / 128;   // 10000
  const int E = in_sizes[1] / 2;     // 80000
  const int* ei = (const int*)d_in[1];

  char* wsp = (char*)d_ws; size_t off = 0;
  auto alloc = [&](size_t bytes) -> void* {
    void* p = wsp + off; off = (off + bytes + 255) & ~(size_t)255; return p;
  };
  int* flag = (int*)alloc(4);
  float* xc = (float*)alloc((size_t)n * 128 * 4);
  unsigned short* xp = (unsigned short*)alloc((size_t)n * 128 * 2);   // packed A, K=128
  unsigned short* W1p = (unsigned short*)alloc((size_t)2048 * 128 * 2);
  unsigned short* W2p = (unsigned short*)alloc((size_t)512 * 64 * 2);
  unsigned short* W3p = (unsigned short*)alloc((size_t)2048 * 128 * 2);
  unsigned short* W4p = (unsigned short*)alloc((size_t)512 * 64 * 2);
  unsigned char* hbuf = (unsigned char*)alloc((size_t)n * 2048);      // fp8
  unsigned char* hbuf2 = hbuf;  // reuse (lifetimes disjoint)
  float* es = (float*)alloc((size_t)n * 32 * 4);
  float* ed = (float*)alloc((size_t)n * 32 * 4);
  unsigned short* xsp = (unsigned short*)alloc((size_t)n * 64 * 2);   // packed A, K=64
  unsigned short* xtp = (unsigned short*)alloc((size_t)n * 64 * 2);
  int* rowA = (int*)alloc((size_t)(n + 1) * 4);
  int* rowB = (int*)alloc((size_t)(n + 1) * 4);
  int* colA = (int*)alloc((size_t)(E + n) * 4);
  int* colB = (int*)alloc((size_t)(E + n) * 4);
  int* degAB = (int*)alloc((size_t)2 * n * 4);
  int* degA = degAB, * degB = degAB + n;
  int* curA = (int*)alloc((size_t)n * 4);
  int* curB = (int*)alloc((size_t)n * 4);

  static const int cidx[32] = {3,4,5, 7,8,9, 11,12,13, 15,16,17,
                               18,19,20,21,22,23,24,25,26,27,28,29,
                               30,31,32,33,34,35,36,37};
  PrepDesc pd;
  float* canon[38] = {nullptr};
  pd.ctotal = 0;
  for (int t = 0; t < 32; ++t) {
    int ii = cidx[t];
    canon[ii] = (float*)alloc((size_t)in_sizes[ii] * 4);
    pd.csrc[t] = d_in[ii];
    pd.cdst[t] = canon[ii];
    pd.cn[t] = in_sizes[ii];
    pd.ctotal += in_sizes[ii];
  }
  pd.x = d_in[0]; pd.xc = xc; pd.xp = xp;
  pd.W1 = d_in[2]; pd.W2 = d_in[6]; pd.W3 = d_in[10]; pd.W4 = d_in[14];
  pd.P1 = W1p; pd.P2 = W2p; pd.P3 = W3p; pd.P4 = W4p;
  pd.degAB = degAB;
  pd.nxb = (n * 128 + 255) / 256;
  pd.xtotal = n * 128;
  pd.ndeg2 = 2 * n;
  (void)ws_size; (void)n_in; (void)out_size;

  // ---- detect + unified prep ----
  k_detect<<<1, 256, 0, stream>>>((const unsigned int*)d_in[0], flag);
  k_prep<<<pd.nxb + 288 + 4 + 8, 256, 0, stream>>>(pd, flag);

  // ---- CSR build (both flows) ----
  k_deg_count<<<(E + 255) / 256, 256, 0, stream>>>(ei, degA, degB, E);
  k_exscan2<<<2, 1024, 0, stream>>>(degA, degB, rowA, rowB, n);
  k_selfloop<<<(n + 255) / 256, 256, 0, stream>>>(rowA, rowB, colA, colB, curA, curB, n);
  k_scatter<<<(E + 255) / 256, 256, 0, stream>>>(ei, colA, colB, curA, curB, E);

  const int mt = n / 16;  // 625
  // ---- Layer 1 (s2t, C=64): x_s ----
  k_mm_es<64,4><<<mt * 32 / 4, 256, 0, stream>>>(xp, W1p, hbuf, canon[3], canon[4], es, ed, n, 2048);
  k_gather64<<<n, 256, 0, stream>>>(hbuf, es, ed, rowA, colA, canon[5], xsp, n);
  // ---- Layer 2 (s2t, C=16): x_in -> out[0] ----
  k_mm_es<16,2><<<mt * 8 / 4, 256, 0, stream>>>(xsp, W2p, hbuf2, canon[7], canon[8], es, ed, n, 512);
  k_gather16<<<n, 256, 0, stream>>>(hbuf2, es, ed, rowA, colA, canon[9], d_out, 0, n, flag);
  // ---- Layer 3 (t2s, C=64): x_t ----
  k_mm_es<64,4><<<mt * 32 / 4, 256, 0, stream>>>(xp, W3p, hbuf, canon[11], canon[12], es, ed, n, 2048);
  k_gather64<<<n, 256, 0, stream>>>(hbuf, es, ed, rowB, colB, canon[13], xtp, n);
  // ---- Layer 4 (t2s, C=16): x_out -> out[1] ----
  k_mm_es<16,2><<<mt * 8 / 4, 256, 0, stream>>>(xtp, W4p, hbuf2, canon[15], canon[16], es, ed, n, 512);
  k_gather16<<<n, 256, 0, stream>>>(hbuf2, es, ed, rowB, colB, canon[17], d_out, (size_t)n * 16, n, flag);
  // ---- Residual MLP: x_self -> out[2] ----
  k_residual<<<n / 16, 256, 0, stream>>>(xc,
      canon[18], canon[19], canon[20], canon[21], canon[22], canon[23],
      canon[24], canon[25], canon[26], canon[27], canon[28], canon[29],
      canon[30], canon[31], canon[32], canon[33], canon[34], canon[35],
      canon[36], canon[37],
      d_out, (size_t)2 * n * 16, n, flag);
}

// Round 7
// 355.358 us; speedup vs baseline: 1.2923x; 1.2649x over previous
//
#include <hip/hip_runtime.h>
#include <stdint.h>

// ---------- bf16 helpers ----------
__device__ __forceinline__ float bf2f(unsigned short u) {
  union { unsigned int i; float f; } v; v.i = ((unsigned int)u) << 16; return v.f;
}
__device__ __forceinline__ unsigned short f2bf(float f) {
  union { float f; unsigned int i; } v; v.f = f;
  unsigned int i = v.i;
  unsigned int r = (i + 0x7fffu + ((i >> 16) & 1u)) >> 16;  // RNE
  return (unsigned short)r;
}

typedef __bf16 bf16x8 __attribute__((ext_vector_type(8)));
typedef float f32x4 __attribute__((ext_vector_type(4)));
union ABfrag { int4 i4; bf16x8 v; };

// ---------- fp8 e4m3fn (OCP) helpers: HW path on gfx950, SW fallback ----------
#if __has_builtin(__builtin_amdgcn_cvt_pk_fp8_f32) && __has_builtin(__builtin_amdgcn_cvt_pk_f32_fp8)
#define HW_FP8 1
#else
#define HW_FP8 0
#endif

__device__ __forceinline__ unsigned char f2fp8_sw(float f) {
  union { float f; unsigned int u; } v; v.f = f;
  unsigned int s = (v.u >> 24) & 0x80;
  float a = fabsf(f);
  if (a >= 448.f) return (unsigned char)(s | 0x7E);
  v.f = a;
  int ex = (int)(v.u >> 23);
  unsigned int man = v.u & 0x7FFFFFu;
  if (ex >= 121) {
    unsigned int val = ((unsigned int)(ex - 120) << 3) | (man >> 20);
    unsigned int rem = man & 0xFFFFFu;
    if (rem > 0x80000u || (rem == 0x80000u && (val & 1))) val++;
    if (val > 0x7E) val = 0x7E;
    return (unsigned char)(s | val);
  }
  int q = (int)(a * 512.f + 0.5f);
  if (q > 8) q = 8;
  return (unsigned char)(s | (unsigned int)q);
}
__device__ __forceinline__ float fp8dec_sw(unsigned char c) {
  unsigned int e = (c >> 3) & 15u, m = c & 7u;
  float v;
  if (e) { union { unsigned int u; float f; } x; x.u = ((e + 120) << 23) | (m << 20); v = x.f; }
  else v = (float)m * 0.001953125f;
  return (c & 0x80) ? -v : v;
}
__device__ __forceinline__ unsigned char f2fp8(float f) {
#if HW_FP8
  int v = __builtin_amdgcn_cvt_pk_fp8_f32(f, f, 0, false);
  return (unsigned char)(v & 0xFF);
#else
  return f2fp8_sw(f);
#endif
}
__device__ __forceinline__ void dec16(int4 g, float o[16]) {
#if HW_FP8
  { auto p = __builtin_amdgcn_cvt_pk_f32_fp8(g.x, false); o[0]=p[0]; o[1]=p[1]; }
  { auto p = __builtin_amdgcn_cvt_pk_f32_fp8(g.x, true ); o[2]=p[0]; o[3]=p[1]; }
  { auto p = __builtin_amdgcn_cvt_pk_f32_fp8(g.y, false); o[4]=p[0]; o[5]=p[1]; }
  { auto p = __builtin_amdgcn_cvt_pk_f32_fp8(g.y, true ); o[6]=p[0]; o[7]=p[1]; }
  { auto p = __builtin_amdgcn_cvt_pk_f32_fp8(g.z, false); o[8]=p[0]; o[9]=p[1]; }
  { auto p = __builtin_amdgcn_cvt_pk_f32_fp8(g.z, true ); o[10]=p[0]; o[11]=p[1]; }
  { auto p = __builtin_amdgcn_cvt_pk_f32_fp8(g.w, false); o[12]=p[0]; o[13]=p[1]; }
  { auto p = __builtin_amdgcn_cvt_pk_f32_fp8(g.w, true ); o[14]=p[0]; o[15]=p[1]; }
#else
  unsigned int w[4] = {(unsigned)g.x, (unsigned)g.y, (unsigned)g.z, (unsigned)g.w};
#pragma unroll
  for (int d = 0; d < 4; ++d)
#pragma unroll
    for (int b = 0; b < 4; ++b) o[d*4+b] = fp8dec_sw((unsigned char)((w[d] >> (b*8)) & 0xFF));
#endif
}

// ---------- dtype detection (bf16-packed vs f32 inputs) ----------
__global__ __launch_bounds__(256) void k_detect(const unsigned int* __restrict__ x, int* flag) {
  __shared__ int cnt;
  if (threadIdx.x == 0) cnt = 0;
  __syncthreads();
  int c = 0;
  for (int i = threadIdx.x; i < 1024; i += 256) {
    unsigned int lo = x[i] & 0xFFFFu;
    int ex = (int)((lo >> 7) & 0xFF);
    if (ex >= 100 && ex <= 140) c++;
  }
  atomicAdd(&cnt, c);
  __syncthreads();
  if (threadIdx.x == 0) flag[0] = (cnt > 600) ? 1 : 0;  // 1 = bf16 inputs
}

// ---------- unified prep: xprep + wpack + canon + deg-zero ----------
struct PrepDesc {
  const void* csrc[32]; float* cdst[32]; int cn[32];
  const void* x; float* xc; unsigned short* xp;
  const void* W1; const void* W2; const void* W3; const void* W4;
  unsigned short* P1; unsigned short* P2; unsigned short* P3; unsigned short* P4;
  int* degAB;
  int nxb;
  int xtotal;
  int ctotal;
  int ndeg2;
};
__global__ __launch_bounds__(256) void k_prep(PrepDesc d, const int* __restrict__ flag) {
  int isbf = *flag;
  int b = blockIdx.x;
  if (b < d.nxb) {
    int i = b * 256 + threadIdx.x;
    if (i < d.xtotal) {
      float v = isbf ? bf2f(((const unsigned short*)d.x)[i]) : ((const float*)d.x)[i];
      d.xc[i] = v;
      int row = i >> 7, c = i & 127;
      int tm = row >> 4, mr = row & 15;
      int s = c >> 5, quad = (c >> 3) & 3, j = c & 7;
      size_t idx = (((size_t)tm * 4 + s) * 64 + quad * 16 + mr) * 8 + j;
      d.xp[idx] = f2bf(v);
    }
    return;
  }
  b -= d.nxb;
  if (b < 288) {
    int u = b * 256 + threadIdx.x;
    const void* W; unsigned short* P; int K, N, lu;
    if (u < 32768)      { W = d.W1; P = d.P1; K = 128; N = 2048; lu = u; }
    else if (u < 36864) { W = d.W2; P = d.P2; K = 64;  N = 512;  lu = u - 32768; }
    else if (u < 69632) { W = d.W3; P = d.P3; K = 128; N = 2048; lu = u - 36864; }
    else                { W = d.W4; P = d.P4; K = 64;  N = 512;  lu = u - 69632; }
    int ksteps = K >> 5;
    int g = lu / (ksteps * 64);
    int rem = lu - g * (ksteps * 64);
    int s = rem >> 6, lane = rem & 63;
    int mr = lane & 15, quad = lane >> 4;
    int col = g * 16 + mr;
    int kbase = s * 32 + quad * 8;
#pragma unroll
    for (int j = 0; j < 8; ++j) {
      size_t src = (size_t)(kbase + j) * N + col;
      float v = isbf ? bf2f(((const unsigned short*)W)[src]) : ((const float*)W)[src];
      P[(size_t)lu * 8 + j] = f2bf(v);
    }
    return;
  }
  b -= 288;
  if (b < 4) {
    for (int idx = b * 256 + threadIdx.x; idx < d.ctotal; idx += 4 * 256) {
      int t = 0, off = idx;
      while (off >= d.cn[t]) { off -= d.cn[t]; ++t; }
      float v = isbf ? bf2f(((const unsigned short*)d.csrc[t])[off])
                     : ((const float*)d.csrc[t])[off];
      d.cdst[t][off] = v;
    }
    return;
  }
  b -= 4;
  for (int idx = b * 256 + threadIdx.x; idx < d.ndeg2; idx += 8 * 256) d.degAB[idx] = 0;
}

// ---------- CSR build ----------
__global__ __launch_bounds__(256) void k_deg_count(const int* __restrict__ ei, int* degA, int* degB, int E) {
  int e = blockIdx.x * 256 + threadIdx.x;
  if (e < E) { atomicAdd(&degA[ei[E + e]], 1); atomicAdd(&degB[ei[e]], 1); }
}
// exclusive scan (+i self-loop slots); also writes self-loop col entry and cur=row+1
__global__ __launch_bounds__(1024) void k_exscan2(const int* __restrict__ degA, const int* __restrict__ degB,
                                                  int* __restrict__ rowA, int* __restrict__ rowB,
                                                  int* __restrict__ colA, int* __restrict__ colB,
                                                  int* __restrict__ curA, int* __restrict__ curB, int n) {
  const int* deg = (blockIdx.x == 0) ? degA : degB;
  int* row = (blockIdx.x == 0) ? rowA : rowB;
  int* colx = (blockIdx.x == 0) ? colA : colB;
  int* curx = (blockIdx.x == 0) ? curA : curB;
  __shared__ int wsum[16], wbase[16];
  __shared__ int carry;
  if (threadIdx.x == 0) carry = 0;
  __syncthreads();
  int lane = threadIdx.x & 63, w = threadIdx.x >> 6;
  int chunks = (n + 1023) >> 10;
  for (int ch = 0; ch < chunks; ++ch) {
    int i = (ch << 10) + threadIdx.x;
    int v = (i < n) ? deg[i] : 0;
    int sc = v;
#pragma unroll
    for (int o = 1; o < 64; o <<= 1) { int t = __shfl_up(sc, o); if (lane >= o) sc += t; }
    if (lane == 63) wsum[w] = sc;
    __syncthreads();
    if (threadIdx.x < 16) {
      int v2 = wsum[threadIdx.x], s2 = v2;
#pragma unroll
      for (int o = 1; o < 16; o <<= 1) { int t = __shfl_up(s2, o); if (lane >= o) s2 += t; }
      wbase[threadIdx.x] = s2 - v2;
      if (threadIdx.x == 15) wsum[15] = s2;
    }
    __syncthreads();
    if (i < n) {
      int rv = carry + wbase[w] + (sc - v) + i;  // +i = self-loop slots
      row[i] = rv;
      colx[rv] = i;        // self-loop first in segment
      curx[i] = rv + 1;
    }
    __syncthreads();
    if (threadIdx.x == 0) carry += wsum[15];
    __syncthreads();
  }
  if (threadIdx.x == 0) row[n] = carry + n;
}
__global__ __launch_bounds__(256) void k_scatter(const int* __restrict__ ei, int* colA, int* colB,
                                                 int* curA, int* curB, int E) {
  int e = blockIdx.x * 256 + threadIdx.x;
  if (e < E) {
    int s = ei[e], d = ei[E + e];
    colA[atomicAdd(&curA[d], 1)] = s;
    colB[atomicAdd(&curB[s], 1)] = d;
  }
}

// ---------- bf16 MFMA matmul (packed A/B) -> fp8 C (LDS-coalesced) + es/ed epilogue ----------
template<int CH, int KSTEPS>
__global__ __launch_bounds__(256) void k_mm_es(const unsigned short* __restrict__ Ap,
                                               const unsigned short* __restrict__ Bp,
                                               unsigned char* __restrict__ C,   // fp8 [M][N]
                                               const float* __restrict__ a_s,
                                               const float* __restrict__ a_d,
                                               float* __restrict__ es, float* __restrict__ ed,
                                               int M, int N) {
  __shared__ unsigned char tile[4][16][64];
  int wid = threadIdx.x >> 6;
  int wg = blockIdx.x * 4 + wid;
  int ntiles = N >> 6;
  int tm = wg / ntiles, tn = wg % ntiles;
  int lane = threadIdx.x & 63;
  int mr = lane & 15, quad = lane >> 4;
  const unsigned short* ap = Ap + ((size_t)tm * KSTEPS) * 512 + lane * 8;
  const unsigned short* bp = Bp + ((size_t)tn * 4 * KSTEPS) * 512 + lane * 8;
  f32x4 acc[4];
#pragma unroll
  for (int i = 0; i < 4; i++) acc[i] = (f32x4){0.f, 0.f, 0.f, 0.f};
#pragma unroll
  for (int s = 0; s < KSTEPS; ++s) {
    ABfrag a; a.i4 = *(const int4*)(ap + s * 512);
#pragma unroll
    for (int nt = 0; nt < 4; ++nt) {
      ABfrag b; b.i4 = *(const int4*)(bp + (size_t)(nt * KSTEPS + s) * 512);
      acc[nt] = __builtin_amdgcn_mfma_f32_16x16x32_bf16(a.v, b.v, acc[nt], 0, 0, 0);
    }
  }
  // ---- stage fp8 tile in LDS, store coalesced (64B segments) ----
#pragma unroll
  for (int nt = 0; nt < 4; ++nt)
#pragma unroll
    for (int r = 0; r < 4; ++r)
      tile[wid][quad * 4 + r][nt * 16 + mr] = f2fp8(acc[nt][r]);
  __syncthreads();
  {
    int r16 = lane >> 2, seg = lane & 3;
    int4 val = *(const int4*)&tile[wid][r16][seg * 16];
    *(int4*)(C + (size_t)(tm * 16 + r16) * N + tn * 64 + seg * 16) = val;
  }
  // ---- fused attention-logit epilogue ----
  if (CH == 64) {
    float pes[4] = {0.f,0.f,0.f,0.f}, ped[4] = {0.f,0.f,0.f,0.f};
    const float* asr = a_s + tn * 64;
    const float* adr = a_d + tn * 64;
#pragma unroll
    for (int nt = 0; nt < 4; ++nt) {
      float ws = asr[nt * 16 + mr], wd = adr[nt * 16 + mr];
#pragma unroll
      for (int r = 0; r < 4; ++r) { pes[r] += acc[nt][r] * ws; ped[r] += acc[nt][r] * wd; }
    }
#pragma unroll
    for (int m = 1; m < 16; m <<= 1)
#pragma unroll
      for (int r = 0; r < 4; ++r) {
        pes[r] += __shfl_xor(pes[r], m);
        ped[r] += __shfl_xor(ped[r], m);
      }
    if (mr == 0) {
#pragma unroll
      for (int r = 0; r < 4; ++r) {
        int row = tm * 16 + quad * 4 + r;
        es[row * 32 + tn] = pes[r];
        ed[row * 32 + tn] = ped[r];
      }
    }
  } else {
    float pes[4][4], ped[4][4];
#pragma unroll
    for (int nt = 0; nt < 4; ++nt) {
      float ws = a_s[(tn * 4 + nt) * 16 + mr];
      float wd = a_d[(tn * 4 + nt) * 16 + mr];
#pragma unroll
      for (int r = 0; r < 4; ++r) { pes[nt][r] = acc[nt][r] * ws; ped[nt][r] = acc[nt][r] * wd; }
    }
#pragma unroll
    for (int m = 1; m < 16; m <<= 1)
#pragma unroll
      for (int nt = 0; nt < 4; ++nt)
#pragma unroll
        for (int r = 0; r < 4; ++r) {
          pes[nt][r] += __shfl_xor(pes[nt][r], m);
          ped[nt][r] += __shfl_xor(ped[nt][r], m);
        }
    if (mr == 0) {
#pragma unroll
      for (int nt = 0; nt < 4; ++nt)
#pragma unroll
        for (int r = 0; r < 4; ++r) {
          int row = tm * 16 + quad * 4 + r;
          es[row * 32 + tn * 4 + nt] = pes[nt][r];
          ed[row * 32 + tn * 4 + nt] = ped[nt][r];
        }
    }
  }
}

__device__ __forceinline__ float lrelu_clamp(float e) {
  e = (e > 0.f) ? e : 0.2f * e;
  return fminf(e, 80.f);
}

// ---------- barrier-free gather, C=64: ONE WAVE per node ----------
// lane covers heads (lane>>2, 16+(lane>>2)) x channels (lane&3)*16+k
__global__ __launch_bounds__(256) void k_gather64(const unsigned char* __restrict__ h,
                                                  const float* __restrict__ es, const float* __restrict__ ed,
                                                  const int* __restrict__ rowp, const int* __restrict__ col,
                                                  const float* __restrict__ bias,
                                                  unsigned short* __restrict__ outp, int n) {
  int wid = threadIdx.x >> 6, lane = threadIdx.x & 63;
  int i = blockIdx.x * 4 + wid;
  if (i >= n) return;
  int hd0 = lane >> 2, hd1 = 16 + hd0;
  float e0 = ed[i * 32 + hd0];
  float e1 = ed[i * 32 + hd1];
  int beg = rowp[i], end = rowp[i + 1];
  int deg = end - beg;
  int colv = (lane < deg) ? col[beg + lane] : 0;
  float acc0[16], acc1[16];
#pragma unroll
  for (int k = 0; k < 16; ++k) { acc0[k] = 0.f; acc1[k] = 0.f; }
  float Z0 = 0.f, Z1 = 0.f;
  for (int j = 0; j < deg; ++j) {
    int s = (j < 64) ? __shfl(colv, j) : col[beg + j];
    const int4* hp = (const int4*)(h + (size_t)s * 2048);
    int4 g0 = hp[lane];
    int4 g1 = hp[64 + lane];
    float q0 = __expf(lrelu_clamp(es[s * 32 + hd0] + e0));
    float q1 = __expf(lrelu_clamp(es[s * 32 + hd1] + e1));
    Z0 += q0; Z1 += q1;
    float d0[16], d1[16];
    dec16(g0, d0); dec16(g1, d1);
#pragma unroll
    for (int k = 0; k < 16; ++k) { acc0[k] += q0 * d0[k]; acc1[k] += q1 * d1[k]; }
  }
  float zi0 = 1.0f / Z0, zi1 = 1.0f / Z1;   // per-head Z complete per lane
  float v[16];
#pragma unroll
  for (int k = 0; k < 16; ++k) v[k] = acc0[k] * zi0 + acc1[k] * zi1;
#pragma unroll
  for (int m = 4; m < 64; m <<= 1)
#pragma unroll
    for (int k = 0; k < 16; ++k) v[k] += __shfl_xor(v[k], m);
  if (lane < 4) {
    int tm = i >> 4, mr = i & 15;
    unsigned short ob[16];
#pragma unroll
    for (int k = 0; k < 16; ++k) {
      float t = v[k] * (1.f / 32.f) + bias[lane * 16 + k];
      t = (t > 0.f) ? t : (__expf(t) - 1.f);   // elu
      ob[k] = f2bf(t);
    }
    int s0 = lane >> 1;
#pragma unroll
    for (int g2 = 0; g2 < 2; ++g2) {
      size_t idx = (((size_t)tm * 2 + s0) * 64 + ((lane & 1) * 2 + g2) * 16 + mr) * 8;
      *(int4*)(outp + idx) = *(const int4*)(ob + g2 * 8);  // packed-A bf16
    }
  }
}

// ---------- barrier-free gather, C=16: ONE WAVE per node -> final output ----------
// lane = (j2 = lane>>5, head hh = lane&31); channels in registers
__global__ __launch_bounds__(256) void k_gather16(const unsigned char* __restrict__ h,
                                                  const float* __restrict__ es, const float* __restrict__ ed,
                                                  const int* __restrict__ rowp, const int* __restrict__ col,
                                                  const float* __restrict__ bias,
                                                  void* __restrict__ outbase, size_t elem_off, int n,
                                                  const int* __restrict__ flag) {
  int wid = threadIdx.x >> 6, lane = threadIdx.x & 63;
  int i = blockIdx.x * 4 + wid;
  if (i >= n) return;
  int hh = lane & 31, j2 = lane >> 5;
  float ev = ed[i * 32 + hh];
  int beg = rowp[i], end = rowp[i + 1];
  int deg = end - beg;
  int colv = (lane < deg) ? col[beg + lane] : 0;
  float acc[16];
#pragma unroll
  for (int k = 0; k < 16; ++k) acc[k] = 0.f;
  float Z = 0.f;
  for (int j = j2; j < deg; j += 2) {
    int s = (j < 64) ? __shfl(colv, j) : col[beg + j];
    int4 g = ((const int4*)(h + (size_t)s * 512))[hh];
    float q = __expf(lrelu_clamp(es[s * 32 + hh] + ev));
    Z += q;
    float d[16];
    dec16(g, d);
#pragma unroll
    for (int k = 0; k < 16; ++k) acc[k] += q * d[k];
  }
  Z += __shfl_xor(Z, 32);           // full Z for head hh
  float zi = 1.0f / Z;
  float v[16];
#pragma unroll
  for (int k = 0; k < 16; ++k) v[k] = acc[k] * zi;
#pragma unroll
  for (int m = 1; m < 64; m <<= 1)
#pragma unroll
    for (int k = 0; k < 16; ++k) v[k] += __shfl_xor(v[k], m);
  if (lane == 0) {
    int isbf = *flag;
    if (isbf) {
      unsigned short ob[16];
#pragma unroll
      for (int k = 0; k < 16; ++k) {
        float t = v[k] * (1.f / 32.f) + bias[k];
        t = (t > 0.f) ? t : (__expf(t) - 1.f);
        ob[k] = f2bf(t);
      }
      unsigned short* o = (unsigned short*)outbase + elem_off + (size_t)i * 16;
      *(int4*)o = *(const int4*)ob;
      *(int4*)(o + 8) = *(const int4*)(ob + 8);
    } else {
      float* o = (float*)outbase + elem_off + (size_t)i * 16;
#pragma unroll
      for (int k = 0; k < 16; ++k) {
        float t = v[k] * (1.f / 32.f) + bias[k];
        t = (t > 0.f) ? t : (__expf(t) - 1.f);
        o[k] = t;
      }
    }
  }
}

// ---------- fused residual network (f32) ----------
__global__ __launch_bounds__(256) void k_residual(const float* __restrict__ x,
    const float* __restrict__ rwa, const float* __restrict__ rba,
    const float* __restrict__ bn1g, const float* __restrict__ bn1b,
    const float* __restrict__ bn1m, const float* __restrict__ bn1v,
    const float* __restrict__ rwb, const float* __restrict__ rbb,
    const float* __restrict__ bn2g, const float* __restrict__ bn2b,
    const float* __restrict__ bn2m, const float* __restrict__ bn2v,
    const float* __restrict__ wsc, const float* __restrict__ bsc,
    const float* __restrict__ bnsg, const float* __restrict__ bnsb,
    const float* __restrict__ bnsm, const float* __restrict__ bnsv,
    const float* __restrict__ wfc, const float* __restrict__ bfc,
    void* __restrict__ outbase, size_t elem_off, int n, const int* __restrict__ flag) {
  __shared__ float xs[16][128];
  __shared__ float ha[16][16];
  __shared__ float tt[16][16];
  int nodebase = blockIdx.x * 16;
  for (int t = threadIdx.x; t < 16 * 128; t += 256)
    xs[t >> 7][t & 127] = x[(size_t)(nodebase + (t >> 7)) * 128 + (t & 127)];
  __syncthreads();
  int ni = threadIdx.x >> 4, c = threadIdx.x & 15;
  float ya = 0.f, ysc = 0.f;
  for (int k = 0; k < 128; ++k) {
    float xv = xs[ni][k];
    ya  += xv * rwa[k * 16 + c];
    ysc += xv * wsc[k * 16 + c];
  }
  ya += rba[c]; ysc += bsc[c];
  float s1 = bn1g[c] * rsqrtf(bn1v[c] + 1e-5f);
  ya = (ya - bn1m[c]) * s1 + bn1b[c];
  ya = fmaxf(ya, 0.f);
  float ss = bnsg[c] * rsqrtf(bnsv[c] + 1e-5f);
  ysc = (ysc - bnsm[c]) * ss + bnsb[c];
  ha[ni][c] = ya;
  __syncthreads();
  float h2 = rbb[c];
  for (int k = 0; k < 16; ++k) h2 += ha[ni][k] * rwb[k * 16 + c];
  float s2 = bn2g[c] * rsqrtf(bn2v[c] + 1e-5f);
  h2 = (h2 - bn2m[c]) * s2 + bn2b[c];
  tt[ni][c] = fmaxf(h2 + ysc, 0.f);
  __syncthreads();
  float o = bfc[c];
  for (int k = 0; k < 16; ++k) o += tt[ni][k] * wfc[k * 16 + c];
  size_t oo = elem_off + (size_t)(nodebase + ni) * 16 + c;
  if (*flag) ((unsigned short*)outbase)[oo] = f2bf(o);
  else       ((float*)outbase)[oo] = o;
}

extern "C" void kernel_launch(void* const* d_in, const int* in_sizes, int n_in,
                              void* d_out, int out_size, void* d_ws, size_t ws_size,
                              hipStream_t stream) {
  const int n = in_sizes[0] / 128;   // 10000
  const int E = in_sizes[1] / 2;     // 80000
  const int* ei = (const int*)d_in[1];

  char* wsp = (char*)d_ws; size_t off = 0;
  auto alloc = [&](size_t bytes) -> void* {
    void* p = wsp + off; off = (off + bytes + 255) & ~(size_t)255; return p;
  };
  int* flag = (int*)alloc(4);
  float* xc = (float*)alloc((size_t)n * 128 * 4);
  unsigned short* xp = (unsigned short*)alloc((size_t)n * 128 * 2);   // packed A, K=128
  unsigned short* W1p = (unsigned short*)alloc((size_t)2048 * 128 * 2);
  unsigned short* W2p = (unsigned short*)alloc((size_t)512 * 64 * 2);
  unsigned short* W3p = (unsigned short*)alloc((size_t)2048 * 128 * 2);
  unsigned short* W4p = (unsigned short*)alloc((size_t)512 * 64 * 2);
  unsigned char* hbuf = (unsigned char*)alloc((size_t)n * 2048);      // fp8
  unsigned char* hbuf2 = hbuf;  // reuse (lifetimes disjoint)
  float* es = (float*)alloc((size_t)n * 32 * 4);
  float* ed = (float*)alloc((size_t)n * 32 * 4);
  unsigned short* xsp = (unsigned short*)alloc((size_t)n * 64 * 2);   // packed A, K=64
  unsigned short* xtp = (unsigned short*)alloc((size_t)n * 64 * 2);
  int* rowA = (int*)alloc((size_t)(n + 1) * 4);
  int* rowB = (int*)alloc((size_t)(n + 1) * 4);
  int* colA = (int*)alloc((size_t)(E + n) * 4);
  int* colB = (int*)alloc((size_t)(E + n) * 4);
  int* degAB = (int*)alloc((size_t)2 * n * 4);
  int* degA = degAB, * degB = degAB + n;
  int* curA = (int*)alloc((size_t)n * 4);
  int* curB = (int*)alloc((size_t)n * 4);

  static const int cidx[32] = {3,4,5, 7,8,9, 11,12,13, 15,16,17,
                               18,19,20,21,22,23,24,25,26,27,28,29,
                               30,31,32,33,34,35,36,37};
  PrepDesc pd;
  float* canon[38] = {nullptr};
  pd.ctotal = 0;
  for (int t = 0; t < 32; ++t) {
    int ii = cidx[t];
    canon[ii] = (float*)alloc((size_t)in_sizes[ii] * 4);
    pd.csrc[t] = d_in[ii];
    pd.cdst[t] = canon[ii];
    pd.cn[t] = in_sizes[ii];
    pd.ctotal += in_sizes[ii];
  }
  pd.x = d_in[0]; pd.xc = xc; pd.xp = xp;
  pd.W1 = d_in[2]; pd.W2 = d_in[6]; pd.W3 = d_in[10]; pd.W4 = d_in[14];
  pd.P1 = W1p; pd.P2 = W2p; pd.P3 = W3p; pd.P4 = W4p;
  pd.degAB = degAB;
  pd.nxb = (n * 128 + 255) / 256;
  pd.xtotal = n * 128;
  pd.ndeg2 = 2 * n;
  (void)ws_size; (void)n_in; (void)out_size;

  // ---- detect + unified prep ----
  k_detect<<<1, 256, 0, stream>>>((const unsigned int*)d_in[0], flag);
  k_prep<<<pd.nxb + 288 + 4 + 8, 256, 0, stream>>>(pd, flag);

  // ---- CSR build (both flows) ----
  k_deg_count<<<(E + 255) / 256, 256, 0, stream>>>(ei, degA, degB, E);
  k_exscan2<<<2, 1024, 0, stream>>>(degA, degB, rowA, rowB, colA, colB, curA, curB, n);
  k_scatter<<<(E + 255) / 256, 256, 0, stream>>>(ei, colA, colB, curA, curB, E);

  const int mt = n / 16;  // 625
  const int gb = (n + 3) / 4;
  // ---- Layer 1 (s2t, C=64): x_s ----
  k_mm_es<64,4><<<mt * 32 / 4, 256, 0, stream>>>(xp, W1p, hbuf, canon[3], canon[4], es, ed, n, 2048);
  k_gather64<<<gb, 256, 0, stream>>>(hbuf, es, ed, rowA, colA, canon[5], xsp, n);
  // ---- Layer 2 (s2t, C=16): x_in -> out[0] ----
  k_mm_es<16,2><<<mt * 8 / 4, 256, 0, stream>>>(xsp, W2p, hbuf2, canon[7], canon[8], es, ed, n, 512);
  k_gather16<<<gb, 256, 0, stream>>>(hbuf2, es, ed, rowA, colA, canon[9], d_out, 0, n, flag);
  // ---- Layer 3 (t2s, C=64): x_t ----
  k_mm_es<64,4><<<mt * 32 / 4, 256, 0, stream>>>(xp, W3p, hbuf, canon[11], canon[12], es, ed, n, 2048);
  k_gather64<<<gb, 256, 0, stream>>>(hbuf, es, ed, rowB, colB, canon[13], xtp, n);
  // ---- Layer 4 (t2s, C=16): x_out -> out[1] ----
  k_mm_es<16,2><<<mt * 8 / 4, 256, 0, stream>>>(xtp, W4p, hbuf2, canon[15], canon[16], es, ed, n, 512);
  k_gather16<<<gb, 256, 0, stream>>>(hbuf2, es, ed, rowB, colB, canon[17], d_out, (size_t)n * 16, n, flag);
  // ---- Residual MLP: x_self -> out[2] ----
  k_residual<<<n / 16, 256, 0, stream>>>(xc,
      canon[18], canon[19], canon[20], canon[21], canon[22], canon[23],
      canon[24], canon[25], canon[26], canon[27], canon[28], canon[29],
      canon[30], canon[31], canon[32], canon[33], canon[34], canon[35],
      canon[36], canon[37],
      d_out, (size_t)2 * n * 16, n, flag);
}

// Round 8
// 323.763 us; speedup vs baseline: 1.4184x; 1.0976x over previous
//
#include <hip/hip_runtime.h>
#include <stdint.h>

// ---------- bf16 helpers ----------
__device__ __forceinline__ float bf2f(unsigned short u) {
  union { unsigned int i; float f; } v; v.i = ((unsigned int)u) << 16; return v.f;
}
__device__ __forceinline__ unsigned short f2bf(float f) {
  union { float f; unsigned int i; } v; v.f = f;
  unsigned int i = v.i;
  unsigned int r = (i + 0x7fffu + ((i >> 16) & 1u)) >> 16;  // RNE
  return (unsigned short)r;
}

typedef __bf16 bf16x8 __attribute__((ext_vector_type(8)));
typedef float f32x4 __attribute__((ext_vector_type(4)));
union ABfrag { int4 i4; bf16x8 v; };

// ---------- fp8 e4m3fn (OCP): HW path on gfx950, SW fallback ----------
#if __has_builtin(__builtin_amdgcn_cvt_pk_fp8_f32) && __has_builtin(__builtin_amdgcn_cvt_pk_f32_fp8)
#define HW_FP8 1
#else
#define HW_FP8 0
#endif

__device__ __forceinline__ unsigned char f2fp8_sw(float f) {
  union { float f; unsigned int u; } v; v.f = f;
  unsigned int s = (v.u >> 24) & 0x80;
  float a = fabsf(f);
  if (a >= 448.f) return (unsigned char)(s | 0x7E);
  v.f = a;
  int ex = (int)(v.u >> 23);
  unsigned int man = v.u & 0x7FFFFFu;
  if (ex >= 121) {
    unsigned int val = ((unsigned int)(ex - 120) << 3) | (man >> 20);
    unsigned int rem = man & 0xFFFFFu;
    if (rem > 0x80000u || (rem == 0x80000u && (val & 1))) val++;
    if (val > 0x7E) val = 0x7E;
    return (unsigned char)(s | val);
  }
  int q = (int)(a * 512.f + 0.5f);
  if (q > 8) q = 8;
  return (unsigned char)(s | (unsigned int)q);
}
__device__ __forceinline__ float fp8dec_sw(unsigned char c) {
  unsigned int e = (c >> 3) & 15u, m = c & 7u;
  float v;
  if (e) { union { unsigned int u; float f; } x; x.u = ((e + 120) << 23) | (m << 20); v = x.f; }
  else v = (float)m * 0.001953125f;
  return (c & 0x80) ? -v : v;
}
__device__ __forceinline__ unsigned char f2fp8(float f) {
#if HW_FP8
  int v = __builtin_amdgcn_cvt_pk_fp8_f32(f, f, 0, false);
  return (unsigned char)(v & 0xFF);
#else
  return f2fp8_sw(f);
#endif
}
__device__ __forceinline__ void dec16(int4 g, float o[16]) {
#if HW_FP8
  { auto p = __builtin_amdgcn_cvt_pk_f32_fp8(g.x, false); o[0]=p[0]; o[1]=p[1]; }
  { auto p = __builtin_amdgcn_cvt_pk_f32_fp8(g.x, true ); o[2]=p[0]; o[3]=p[1]; }
  { auto p = __builtin_amdgcn_cvt_pk_f32_fp8(g.y, false); o[4]=p[0]; o[5]=p[1]; }
  { auto p = __builtin_amdgcn_cvt_pk_f32_fp8(g.y, true ); o[6]=p[0]; o[7]=p[1]; }
  { auto p = __builtin_amdgcn_cvt_pk_f32_fp8(g.z, false); o[8]=p[0]; o[9]=p[1]; }
  { auto p = __builtin_amdgcn_cvt_pk_f32_fp8(g.z, true ); o[10]=p[0]; o[11]=p[1]; }
  { auto p = __builtin_amdgcn_cvt_pk_f32_fp8(g.w, false); o[12]=p[0]; o[13]=p[1]; }
  { auto p = __builtin_amdgcn_cvt_pk_f32_fp8(g.w, true ); o[14]=p[0]; o[15]=p[1]; }
#else
  unsigned int w[4] = {(unsigned)g.x, (unsigned)g.y, (unsigned)g.z, (unsigned)g.w};
#pragma unroll
  for (int d = 0; d < 4; ++d)
#pragma unroll
    for (int b = 0; b < 4; ++b) o[d*4+b] = fp8dec_sw((unsigned char)((w[d] >> (b*8)) & 0xFF));
#endif
}

__device__ __forceinline__ float lrelu_clamp(float e) {
  e = (e > 0.f) ? e : 0.2f * e;
  return fminf(e, 80.f);
}

// ---------- dtype detection ----------
__global__ __launch_bounds__(256) void k_detect(const unsigned int* __restrict__ x, int* flag) {
  __shared__ int cnt;
  if (threadIdx.x == 0) cnt = 0;
  __syncthreads();
  int c = 0;
  for (int i = threadIdx.x; i < 1024; i += 256) {
    unsigned int lo = x[i] & 0xFFFFu;
    int ex = (int)((lo >> 7) & 0xFF);
    if (ex >= 100 && ex <= 140) c++;
  }
  atomicAdd(&cnt, c);
  __syncthreads();
  if (threadIdx.x == 0) flag[0] = (cnt > 600) ? 1 : 0;  // 1 = bf16 inputs
}

// ---------- unified prep ----------
struct PrepDesc {
  const void* csrc[32]; float* cdst[32]; int cn[32];
  const void* x; float* xc; unsigned short* xp;
  const void* W1; const void* W2; const void* W3; const void* W4;
  unsigned short* P1; unsigned short* P2; unsigned short* P3; unsigned short* P4;
  int* degAB;
  int nxb, xtotal, ctotal, ndeg2;
};
__global__ __launch_bounds__(256) void k_prep(PrepDesc d, const int* __restrict__ flag) {
  int isbf = *flag;
  int b = blockIdx.x;
  if (b < d.nxb) {
    int i = b * 256 + threadIdx.x;
    if (i < d.xtotal) {
      float v = isbf ? bf2f(((const unsigned short*)d.x)[i]) : ((const float*)d.x)[i];
      d.xc[i] = v;
      int row = i >> 7, c = i & 127;
      int tm = row >> 4, mr = row & 15;
      int s = c >> 5, quad = (c >> 3) & 3, j = c & 7;
      size_t idx = (((size_t)tm * 4 + s) * 64 + quad * 16 + mr) * 8 + j;
      d.xp[idx] = f2bf(v);
    }
    return;
  }
  b -= d.nxb;
  if (b < 288) {
    int u = b * 256 + threadIdx.x;
    const void* W; unsigned short* P; int K, N, lu;
    if (u < 32768)      { W = d.W1; P = d.P1; K = 128; N = 2048; lu = u; }
    else if (u < 36864) { W = d.W2; P = d.P2; K = 64;  N = 512;  lu = u - 32768; }
    else if (u < 69632) { W = d.W3; P = d.P3; K = 128; N = 2048; lu = u - 36864; }
    else                { W = d.W4; P = d.P4; K = 64;  N = 512;  lu = u - 69632; }
    int ksteps = K >> 5;
    int g = lu / (ksteps * 64);
    int rem = lu - g * (ksteps * 64);
    int s = rem >> 6, lane = rem & 63;
    int mr = lane & 15, quad = lane >> 4;
    int col = g * 16 + mr;
    int kbase = s * 32 + quad * 8;
#pragma unroll
    for (int j = 0; j < 8; ++j) {
      size_t src = (size_t)(kbase + j) * N + col;
      float v = isbf ? bf2f(((const unsigned short*)W)[src]) : ((const float*)W)[src];
      P[(size_t)lu * 8 + j] = f2bf(v);
    }
    return;
  }
  b -= 288;
  if (b < 4) {
    for (int idx = b * 256 + threadIdx.x; idx < d.ctotal; idx += 4 * 256) {
      int t = 0, off = idx;
      while (off >= d.cn[t]) { off -= d.cn[t]; ++t; }
      float v = isbf ? bf2f(((const unsigned short*)d.csrc[t])[off])
                     : ((const float*)d.csrc[t])[off];
      d.cdst[t][off] = v;
    }
    return;
  }
  b -= 4;
  for (int idx = b * 256 + threadIdx.x; idx < d.ndeg2; idx += 8 * 256) d.degAB[idx] = 0;
}

// ---------- CSR build ----------
__global__ __launch_bounds__(256) void k_deg_count(const int* __restrict__ ei, int* degA, int* degB, int E) {
  int e = blockIdx.x * 256 + threadIdx.x;
  if (e < E) { atomicAdd(&degA[ei[E + e]], 1); atomicAdd(&degB[ei[e]], 1); }
}
__global__ __launch_bounds__(1024) void k_exscan2(const int* __restrict__ degA, const int* __restrict__ degB,
                                                  int* __restrict__ rowA, int* __restrict__ rowB,
                                                  int* __restrict__ colA, int* __restrict__ colB,
                                                  int* __restrict__ curA, int* __restrict__ curB, int n) {
  const int* deg = (blockIdx.x == 0) ? degA : degB;
  int* row = (blockIdx.x == 0) ? rowA : rowB;
  int* colx = (blockIdx.x == 0) ? colA : colB;
  int* curx = (blockIdx.x == 0) ? curA : curB;
  __shared__ int wsum[16], wbase[16];
  __shared__ int carry;
  if (threadIdx.x == 0) carry = 0;
  __syncthreads();
  int lane = threadIdx.x & 63, w = threadIdx.x >> 6;
  int chunks = (n + 1023) >> 10;
  for (int ch = 0; ch < chunks; ++ch) {
    int i = (ch << 10) + threadIdx.x;
    int v = (i < n) ? deg[i] : 0;
    int sc = v;
#pragma unroll
    for (int o = 1; o < 64; o <<= 1) { int t = __shfl_up(sc, o); if (lane >= o) sc += t; }
    if (lane == 63) wsum[w] = sc;
    __syncthreads();
    if (threadIdx.x < 16) {
      int v2 = wsum[threadIdx.x], s2 = v2;
#pragma unroll
      for (int o = 1; o < 16; o <<= 1) { int t = __shfl_up(s2, o); if (lane >= o) s2 += t; }
      wbase[threadIdx.x] = s2 - v2;
      if (threadIdx.x == 15) wsum[15] = s2;
    }
    __syncthreads();
    if (i < n) {
      int rv = carry + wbase[w] + (sc - v) + i;
      row[i] = rv;
      colx[rv] = i;
      curx[i] = rv + 1;
    }
    __syncthreads();
    if (threadIdx.x == 0) carry += wsum[15];
    __syncthreads();
  }
  if (threadIdx.x == 0) row[n] = carry + n;
}
__global__ __launch_bounds__(256) void k_scatter(const int* __restrict__ ei, int* colA, int* colB,
                                                 int* curA, int* curB, int E) {
  int e = blockIdx.x * 256 + threadIdx.x;
  if (e < E) {
    int s = ei[e], d = ei[E + e];
    colA[atomicAdd(&curA[d], 1)] = s;
    colB[atomicAdd(&curB[s], 1)] = d;
  }
}

// ---------- shared-mem union for the merged mm13+residual kernel ----------
union SMem {
  unsigned char tile[4][16][64];
  struct { float xs[16][128]; float ha[16][16]; float tt[16][16]; } res;
};

// ---------- mm_es device body (packed A/B -> fp8 C + es/ed) ----------
template<int CH, int KSTEPS>
__device__ __forceinline__ void mm_es_body(int vblk,
    const unsigned short* __restrict__ Ap, const unsigned short* __restrict__ Bp,
    unsigned char* __restrict__ C, const float* __restrict__ a_s, const float* __restrict__ a_d,
    float* __restrict__ es, float* __restrict__ ed, int N, SMem* sm) {
  int wid = threadIdx.x >> 6;
  int wg = vblk * 4 + wid;
  int ntiles = N >> 6;
  int tm = wg / ntiles, tn = wg % ntiles;
  int lane = threadIdx.x & 63;
  int mr = lane & 15, quad = lane >> 4;
  const unsigned short* ap = Ap + ((size_t)tm * KSTEPS) * 512 + lane * 8;
  const unsigned short* bp = Bp + ((size_t)tn * 4 * KSTEPS) * 512 + lane * 8;
  f32x4 acc[4];
#pragma unroll
  for (int i = 0; i < 4; i++) acc[i] = (f32x4){0.f, 0.f, 0.f, 0.f};
#pragma unroll
  for (int s = 0; s < KSTEPS; ++s) {
    ABfrag a; a.i4 = *(const int4*)(ap + s * 512);
#pragma unroll
    for (int nt = 0; nt < 4; ++nt) {
      ABfrag b; b.i4 = *(const int4*)(bp + (size_t)(nt * KSTEPS + s) * 512);
      acc[nt] = __builtin_amdgcn_mfma_f32_16x16x32_bf16(a.v, b.v, acc[nt], 0, 0, 0);
    }
  }
#pragma unroll
  for (int nt = 0; nt < 4; ++nt)
#pragma unroll
    for (int r = 0; r < 4; ++r)
      sm->tile[wid][quad * 4 + r][nt * 16 + mr] = f2fp8(acc[nt][r]);
  __syncthreads();
  {
    int r16 = lane >> 2, seg = lane & 3;
    int4 val = *(const int4*)&sm->tile[wid][r16][seg * 16];
    *(int4*)(C + (size_t)(tm * 16 + r16) * N + tn * 64 + seg * 16) = val;
  }
  if (CH == 64) {
    float pes[4] = {0.f,0.f,0.f,0.f}, ped[4] = {0.f,0.f,0.f,0.f};
    const float* asr = a_s + tn * 64;
    const float* adr = a_d + tn * 64;
#pragma unroll
    for (int nt = 0; nt < 4; ++nt) {
      float ws = asr[nt * 16 + mr], wd = adr[nt * 16 + mr];
#pragma unroll
      for (int r = 0; r < 4; ++r) { pes[r] += acc[nt][r] * ws; ped[r] += acc[nt][r] * wd; }
    }
#pragma unroll
    for (int m = 1; m < 16; m <<= 1)
#pragma unroll
      for (int r = 0; r < 4; ++r) {
        pes[r] += __shfl_xor(pes[r], m);
        ped[r] += __shfl_xor(ped[r], m);
      }
    if (mr == 0) {
#pragma unroll
      for (int r = 0; r < 4; ++r) {
        int row = tm * 16 + quad * 4 + r;
        es[row * 32 + tn] = pes[r];
        ed[row * 32 + tn] = ped[r];
      }
    }
  } else {
    float pes[4][4], ped[4][4];
#pragma unroll
    for (int nt = 0; nt < 4; ++nt) {
      float ws = a_s[(tn * 4 + nt) * 16 + mr];
      float wd = a_d[(tn * 4 + nt) * 16 + mr];
#pragma unroll
      for (int r = 0; r < 4; ++r) { pes[nt][r] = acc[nt][r] * ws; ped[nt][r] = acc[nt][r] * wd; }
    }
#pragma unroll
    for (int m = 1; m < 16; m <<= 1)
#pragma unroll
      for (int nt = 0; nt < 4; ++nt)
#pragma unroll
        for (int r = 0; r < 4; ++r) {
          pes[nt][r] += __shfl_xor(pes[nt][r], m);
          ped[nt][r] += __shfl_xor(ped[nt][r], m);
        }
    if (mr == 0) {
#pragma unroll
      for (int nt = 0; nt < 4; ++nt)
#pragma unroll
        for (int r = 0; r < 4; ++r) {
          int row = tm * 16 + quad * 4 + r;
          es[row * 32 + tn * 4 + nt] = pes[nt][r];
          ed[row * 32 + tn * 4 + nt] = ped[nt][r];
        }
    }
  }
}

// ---------- merged: mm1 + mm3 + residual MLP ----------
struct MM13Desc {
  const unsigned short* Ap;
  const unsigned short* B1; const unsigned short* B3;
  unsigned char* C1; unsigned char* C3;
  const float* as1; const float* ad1; const float* as3; const float* ad3;
  float* es1; float* ed1; float* es3; float* ed3;
  int mmblks;          // 5000 per flow
  // residual
  const float* xc;
  const float* rp[20]; // rwa,rba,bn1g,bn1b,bn1m,bn1v,rwb,rbb,bn2g,bn2b,bn2m,bn2v,wsc,bsc,bnsg,bnsb,bnsm,bnsv,wfc,bfc
  void* outbase; size_t eoff; int n;
  const int* flag;
};
__global__ __launch_bounds__(256) void k_mm13res(MM13Desc d) {
  __shared__ SMem sm;
  int b = blockIdx.x;
  if (b < d.mmblks) {
    mm_es_body<64,4>(b, d.Ap, d.B1, d.C1, d.as1, d.ad1, d.es1, d.ed1, 2048, &sm);
    return;
  }
  b -= d.mmblks;
  if (b < d.mmblks) {
    mm_es_body<64,4>(b, d.Ap, d.B3, d.C3, d.as3, d.ad3, d.es3, d.ed3, 2048, &sm);
    return;
  }
  b -= d.mmblks;
  // ---- residual MLP: 16 nodes x 16 ch per block ----
  int nodebase = b * 16;
  for (int t = threadIdx.x; t < 16 * 128; t += 256)
    sm.res.xs[t >> 7][t & 127] = d.xc[(size_t)(nodebase + (t >> 7)) * 128 + (t & 127)];
  __syncthreads();
  int ni = threadIdx.x >> 4, c = threadIdx.x & 15;
  const float* rwa = d.rp[0]; const float* rba = d.rp[1];
  const float* bn1g = d.rp[2]; const float* bn1b = d.rp[3];
  const float* bn1m = d.rp[4]; const float* bn1v = d.rp[5];
  const float* rwb = d.rp[6]; const float* rbb = d.rp[7];
  const float* bn2g = d.rp[8]; const float* bn2b = d.rp[9];
  const float* bn2m = d.rp[10]; const float* bn2v = d.rp[11];
  const float* wsc = d.rp[12]; const float* bsc = d.rp[13];
  const float* bnsg = d.rp[14]; const float* bnsb = d.rp[15];
  const float* bnsm = d.rp[16]; const float* bnsv = d.rp[17];
  const float* wfc = d.rp[18]; const float* bfc = d.rp[19];
  float ya = 0.f, ysc = 0.f;
  for (int k = 0; k < 128; ++k) {
    float xv = sm.res.xs[ni][k];
    ya  += xv * rwa[k * 16 + c];
    ysc += xv * wsc[k * 16 + c];
  }
  ya += rba[c]; ysc += bsc[c];
  float s1 = bn1g[c] * rsqrtf(bn1v[c] + 1e-5f);
  ya = (ya - bn1m[c]) * s1 + bn1b[c];
  ya = fmaxf(ya, 0.f);
  float ss = bnsg[c] * rsqrtf(bnsv[c] + 1e-5f);
  ysc = (ysc - bnsm[c]) * ss + bnsb[c];
  sm.res.ha[ni][c] = ya;
  __syncthreads();
  float h2 = rbb[c];
  for (int k = 0; k < 16; ++k) h2 += sm.res.ha[ni][k] * rwb[k * 16 + c];
  float s2 = bn2g[c] * rsqrtf(bn2v[c] + 1e-5f);
  h2 = (h2 - bn2m[c]) * s2 + bn2b[c];
  sm.res.tt[ni][c] = fmaxf(h2 + ysc, 0.f);
  __syncthreads();
  float o = bfc[c];
  for (int k = 0; k < 16; ++k) o += sm.res.tt[ni][k] * wfc[k * 16 + c];
  size_t oo = d.eoff + (size_t)(nodebase + ni) * 16 + c;
  if (*d.flag) ((unsigned short*)d.outbase)[oo] = f2bf(o);
  else         ((float*)d.outbase)[oo] = o;
}

// ---------- merged gather64, both flows; ONE WAVE per node ----------
__global__ __launch_bounds__(256) void k_g64(const unsigned char* __restrict__ h1,
                                             const unsigned char* __restrict__ h3,
                                             const float* __restrict__ es1, const float* __restrict__ ed1,
                                             const float* __restrict__ es3, const float* __restrict__ ed3,
                                             const int* __restrict__ rowA, const int* __restrict__ colA,
                                             const int* __restrict__ rowB, const int* __restrict__ colB,
                                             const float* __restrict__ b1, const float* __restrict__ b3,
                                             unsigned short* __restrict__ xsp, unsigned short* __restrict__ xtp,
                                             int n, int gb) {
  int b = blockIdx.x;
  const unsigned char* h; const float *es, *ed, *bias; const int *rowp, *col; unsigned short* outp;
  if (b < gb) { h = h1; es = es1; ed = ed1; rowp = rowA; col = colA; bias = b1; outp = xsp; }
  else { b -= gb; h = h3; es = es3; ed = ed3; rowp = rowB; col = colB; bias = b3; outp = xtp; }
  int wid = threadIdx.x >> 6, lane = threadIdx.x & 63;
  int i = b * 4 + wid;
  if (i >= n) return;
  int hd0 = lane >> 2, hd1 = 16 + hd0;
  float e0 = ed[i * 32 + hd0];
  float e1 = ed[i * 32 + hd1];
  int beg = rowp[i], end = rowp[i + 1];
  int deg = end - beg;
  int colv = (lane < deg) ? col[beg + lane] : 0;
  float acc0[16], acc1[16];
#pragma unroll
  for (int k = 0; k < 16; ++k) { acc0[k] = 0.f; acc1[k] = 0.f; }
  float Z0 = 0.f, Z1 = 0.f;
  for (int j = 0; j < deg; ++j) {
    int s = (j < 64) ? __shfl(colv, j) : col[beg + j];
    const int4* hp = (const int4*)(h + (size_t)s * 2048);
    int4 g0 = hp[lane];
    int4 g1 = hp[64 + lane];
    float q0 = __expf(lrelu_clamp(es[s * 32 + hd0] + e0));
    float q1 = __expf(lrelu_clamp(es[s * 32 + hd1] + e1));
    Z0 += q0; Z1 += q1;
    float d0[16], d1[16];
    dec16(g0, d0); dec16(g1, d1);
#pragma unroll
    for (int k = 0; k < 16; ++k) { acc0[k] += q0 * d0[k]; acc1[k] += q1 * d1[k]; }
  }
  float zi0 = 1.0f / Z0, zi1 = 1.0f / Z1;
  float v[16];
#pragma unroll
  for (int k = 0; k < 16; ++k) v[k] = acc0[k] * zi0 + acc1[k] * zi1;
#pragma unroll
  for (int m = 4; m < 64; m <<= 1)
#pragma unroll
    for (int k = 0; k < 16; ++k) v[k] += __shfl_xor(v[k], m);
  if (lane < 4) {
    int tm = i >> 4, mr = i & 15;
    unsigned short ob[16];
#pragma unroll
    for (int k = 0; k < 16; ++k) {
      float t = v[k] * (1.f / 32.f) + bias[lane * 16 + k];
      t = (t > 0.f) ? t : (__expf(t) - 1.f);   // elu
      ob[k] = f2bf(t);
    }
    int s0 = lane >> 1;
#pragma unroll
    for (int g2 = 0; g2 < 2; ++g2) {
      size_t idx = (((size_t)tm * 2 + s0) * 64 + ((lane & 1) * 2 + g2) * 16 + mr) * 8;
      *(int4*)(outp + idx) = *(const int4*)(ob + g2 * 8);  // packed-A bf16
    }
  }
}

// ---------- merged mm2 + mm4 ----------
__global__ __launch_bounds__(256) void k_mm24(const unsigned short* __restrict__ xsp,
                                              const unsigned short* __restrict__ xtp,
                                              const unsigned short* __restrict__ W2p,
                                              const unsigned short* __restrict__ W4p,
                                              unsigned char* __restrict__ h2, unsigned char* __restrict__ h4,
                                              const float* __restrict__ as2, const float* __restrict__ ad2,
                                              const float* __restrict__ as4, const float* __restrict__ ad4,
                                              float* __restrict__ es2, float* __restrict__ ed2,
                                              float* __restrict__ es4, float* __restrict__ ed4,
                                              int mmblks) {
  __shared__ SMem sm;
  int b = blockIdx.x;
  if (b < mmblks)
    mm_es_body<16,2>(b, xsp, W2p, h2, as2, ad2, es2, ed2, 512, &sm);
  else
    mm_es_body<16,2>(b - mmblks, xtp, W4p, h4, as4, ad4, es4, ed4, 512, &sm);
}

// ---------- merged gather16, both flows; ONE WAVE per node -> final outputs ----------
__global__ __launch_bounds__(256) void k_g16(const unsigned char* __restrict__ h2,
                                             const unsigned char* __restrict__ h4,
                                             const float* __restrict__ es2, const float* __restrict__ ed2,
                                             const float* __restrict__ es4, const float* __restrict__ ed4,
                                             const int* __restrict__ rowA, const int* __restrict__ colA,
                                             const int* __restrict__ rowB, const int* __restrict__ colB,
                                             const float* __restrict__ b2, const float* __restrict__ b4,
                                             void* __restrict__ outbase, int n, int gb,
                                             const int* __restrict__ flag) {
  int b = blockIdx.x;
  const unsigned char* h; const float *es, *ed, *bias; const int *rowp, *col; size_t eoff;
  if (b < gb) { h = h2; es = es2; ed = ed2; rowp = rowA; col = colA; bias = b2; eoff = 0; }
  else { b -= gb; h = h4; es = es4; ed = ed4; rowp = rowB; col = colB; bias = b4; eoff = (size_t)n * 16; }
  int wid = threadIdx.x >> 6, lane = threadIdx.x & 63;
  int i = b * 4 + wid;
  if (i >= n) return;
  int hh = lane & 31, j2 = lane >> 5;
  float ev = ed[i * 32 + hh];
  int beg = rowp[i], end = rowp[i + 1];
  int deg = end - beg;
  int colv = (lane < deg) ? col[beg + lane] : 0;
  float acc[16];
#pragma unroll
  for (int k = 0; k < 16; ++k) acc[k] = 0.f;
  float Z = 0.f;
  for (int j = j2; j < deg; j += 2) {
    int s = (j < 64) ? __shfl(colv, j) : col[beg + j];
    int4 g = ((const int4*)(h + (size_t)s * 512))[hh];
    float q = __expf(lrelu_clamp(es[s * 32 + hh] + ev));
    Z += q;
    float d[16];
    dec16(g, d);
#pragma unroll
    for (int k = 0; k < 16; ++k) acc[k] += q * d[k];
  }
  Z += __shfl_xor(Z, 32);
  float zi = 1.0f / Z;
  float v[16];
#pragma unroll
  for (int k = 0; k < 16; ++k) v[k] = acc[k] * zi;
#pragma unroll
  for (int m = 1; m < 64; m <<= 1)
#pragma unroll
    for (int k = 0; k < 16; ++k) v[k] += __shfl_xor(v[k], m);
  if (lane == 0) {
    int isbf = *flag;
    if (isbf) {
      unsigned short ob[16];
#pragma unroll
      for (int k = 0; k < 16; ++k) {
        float t = v[k] * (1.f / 32.f) + bias[k];
        t = (t > 0.f) ? t : (__expf(t) - 1.f);
        ob[k] = f2bf(t);
      }
      unsigned short* o = (unsigned short*)outbase + eoff + (size_t)i * 16;
      *(int4*)o = *(const int4*)ob;
      *(int4*)(o + 8) = *(const int4*)(ob + 8);
    } else {
      float* o = (float*)outbase + eoff + (size_t)i * 16;
#pragma unroll
      for (int k = 0; k < 16; ++k) {
        float t = v[k] * (1.f / 32.f) + bias[k];
        t = (t > 0.f) ? t : (__expf(t) - 1.f);
        o[k] = t;
      }
    }
  }
}

extern "C" void kernel_launch(void* const* d_in, const int* in_sizes, int n_in,
                              void* d_out, int out_size, void* d_ws, size_t ws_size,
                              hipStream_t stream) {
  const int n = in_sizes[0] / 128;   // 10000
  const int E = in_sizes[1] / 2;     // 80000
  const int* ei = (const int*)d_in[1];

  char* wsp = (char*)d_ws; size_t off = 0;
  auto alloc = [&](size_t bytes) -> void* {
    void* p = wsp + off; off = (off + bytes + 255) & ~(size_t)255; return p;
  };
  int* flag = (int*)alloc(4);
  float* xc = (float*)alloc((size_t)n * 128 * 4);
  unsigned short* xp = (unsigned short*)alloc((size_t)n * 128 * 2);
  unsigned short* W1p = (unsigned short*)alloc((size_t)2048 * 128 * 2);
  unsigned short* W2p = (unsigned short*)alloc((size_t)512 * 64 * 2);
  unsigned short* W3p = (unsigned short*)alloc((size_t)2048 * 128 * 2);
  unsigned short* W4p = (unsigned short*)alloc((size_t)512 * 64 * 2);
  unsigned char* h1 = (unsigned char*)alloc((size_t)n * 2048);   // fp8
  unsigned char* h3 = (unsigned char*)alloc((size_t)n * 2048);
  unsigned char* h2 = (unsigned char*)alloc((size_t)n * 512);
  unsigned char* h4 = (unsigned char*)alloc((size_t)n * 512);
  float* es1 = (float*)alloc((size_t)n * 32 * 4);
  float* ed1 = (float*)alloc((size_t)n * 32 * 4);
  float* es3 = (float*)alloc((size_t)n * 32 * 4);
  float* ed3 = (float*)alloc((size_t)n * 32 * 4);
  float* es2 = (float*)alloc((size_t)n * 32 * 4);
  float* ed2 = (float*)alloc((size_t)n * 32 * 4);
  float* es4 = (float*)alloc((size_t)n * 32 * 4);
  float* ed4 = (float*)alloc((size_t)n * 32 * 4);
  unsigned short* xsp = (unsigned short*)alloc((size_t)n * 64 * 2);
  unsigned short* xtp = (unsigned short*)alloc((size_t)n * 64 * 2);
  int* rowA = (int*)alloc((size_t)(n + 1) * 4);
  int* rowB = (int*)alloc((size_t)(n + 1) * 4);
  int* colA = (int*)alloc((size_t)(E + n) * 4);
  int* colB = (int*)alloc((size_t)(E + n) * 4);
  int* degAB = (int*)alloc((size_t)2 * n * 4);
  int* degA = degAB, * degB = degAB + n;
  int* curA = (int*)alloc((size_t)n * 4);
  int* curB = (int*)alloc((size_t)n * 4);

  static const int cidx[32] = {3,4,5, 7,8,9, 11,12,13, 15,16,17,
                               18,19,20,21,22,23,24,25,26,27,28,29,
                               30,31,32,33,34,35,36,37};
  PrepDesc pd;
  float* canon[38] = {nullptr};
  pd.ctotal = 0;
  for (int t = 0; t < 32; ++t) {
    int ii = cidx[t];
    canon[ii] = (float*)alloc((size_t)in_sizes[ii] * 4);
    pd.csrc[t] = d_in[ii];
    pd.cdst[t] = canon[ii];
    pd.cn[t] = in_sizes[ii];
    pd.ctotal += in_sizes[ii];
  }
  pd.x = d_in[0]; pd.xc = xc; pd.xp = xp;
  pd.W1 = d_in[2]; pd.W2 = d_in[6]; pd.W3 = d_in[10]; pd.W4 = d_in[14];
  pd.P1 = W1p; pd.P2 = W2p; pd.P3 = W3p; pd.P4 = W4p;
  pd.degAB = degAB;
  pd.nxb = (n * 128 + 255) / 256;
  pd.xtotal = n * 128;
  pd.ndeg2 = 2 * n;
  (void)ws_size; (void)n_in; (void)out_size;

  // ---- detect + unified prep ----
  k_detect<<<1, 256, 0, stream>>>((const unsigned int*)d_in[0], flag);
  k_prep<<<pd.nxb + 288 + 4 + 8, 256, 0, stream>>>(pd, flag);

  // ---- CSR build (both flows) ----
  k_deg_count<<<(E + 255) / 256, 256, 0, stream>>>(ei, degA, degB, E);
  k_exscan2<<<2, 1024, 0, stream>>>(degA, degB, rowA, rowB, colA, colB, curA, curB, n);
  k_scatter<<<(E + 255) / 256, 256, 0, stream>>>(ei, colA, colB, curA, curB, E);

  const int mt = n / 16;            // 625
  const int mmblks64 = mt * 32 / 4; // 5000
  const int mmblks16 = mt * 8 / 4;  // 1250
  const int gb = (n + 3) / 4;       // 2500

  // ---- stage 1: mm1 + mm3 + residual ----
  MM13Desc md;
  md.Ap = xp; md.B1 = W1p; md.B3 = W3p; md.C1 = h1; md.C3 = h3;
  md.as1 = canon[3]; md.ad1 = canon[4]; md.as3 = canon[11]; md.ad3 = canon[12];
  md.es1 = es1; md.ed1 = ed1; md.es3 = es3; md.ed3 = ed3;
  md.mmblks = mmblks64;
  md.xc = xc;
  for (int t = 0; t < 20; ++t) md.rp[t] = canon[18 + t];
  md.outbase = d_out; md.eoff = (size_t)2 * n * 16; md.n = n; md.flag = flag;
  k_mm13res<<<2 * mmblks64 + n / 16, 256, 0, stream>>>(md);

  // ---- stage 2: gather64 both flows ----
  k_g64<<<2 * gb, 256, 0, stream>>>(h1, h3, es1, ed1, es3, ed3,
                                    rowA, colA, rowB, colB,
                                    canon[5], canon[13], xsp, xtp, n, gb);
  // ---- stage 3: mm2 + mm4 ----
  k_mm24<<<2 * mmblks16, 256, 0, stream>>>(xsp, xtp, W2p, W4p, h2, h4,
                                           canon[7], canon[8], canon[15], canon[16],
                                           es2, ed2, es4, ed4, mmblks16);
  // ---- stage 4: gather16 both flows -> outputs 0,1 ----
  k_g16<<<2 * gb, 256, 0, stream>>>(h2, h4, es2, ed2, es4, ed4,
                                    rowA, colA, rowB, colB,
                                    canon[9], canon[17], d_out, n, gb, flag);
}